// Round 2
// baseline (542.752 us; speedup 1.0000x reference)
//
#include <hip/hip_runtime.h>

#define B_ 2048
#define S_ 50
#define E_ 300
#define NPAIR 44850
#define KSPLIT 12
#define R_ (B_ * S_)            // 102400 rows for attn fc
#define PADSCORE (-4294967295.0f)
#define RSBLK 512               // blocks for k_reduce_stat (4 rows each)
#define RSROWS (B_ / RSBLK)

typedef _Float16 h8 __attribute__((ext_vector_type(8)));
typedef float f4 __attribute__((ext_vector_type(4)));

// ---------- chunk metadata: each 32-wide k-chunk has a single i, 8-aligned j0 ----------
__global__ void k_meta(int* __restrict__ meta) {
  __shared__ int cnt[304], start[304];
  int i = threadIdx.x;
  if (i < 299) {
    int js = (i + 1) & ~7;
    cnt[i] = (300 - js + 31) >> 5;
  }
  __syncthreads();
  if (threadIdx.x == 0) {
    int s = 0;
    for (int r = 0; r < 299; r++) { start[r] = s; s += cnt[r]; }
  }
  __syncthreads();
  if (i < 299) {
    int js = (i + 1) & ~7;
    for (int c = 0; c < cnt[i]; c++)
      meta[start[i] + c] = i | ((js + 32 * c) << 16);
  }
}

// ---------- Wgf in MFMA B-fragment order (cross-feature weights * g) ----------
__global__ __launch_bounds__(256) void k_wg3(
    const float* __restrict__ w7, const float* __restrict__ v,
    const int* __restrict__ meta, _Float16* __restrict__ Wgf) {
  __shared__ float gL[32];
  const int ch = blockIdx.x;
  const int mt = meta[ch];
  const int i = mt & 0xffff, j0 = mt >> 16;
  const int t = threadIdx.x;
  if (t < 32) {
    int j = j0 + t;
    float g = 0.f;
    if (j > i && j < 300)
      g = v[i*4+0]*v[j*4+0] + v[i*4+1]*v[j*4+1] + v[i*4+2]*v[j*4+2] + v[i*4+3]*v[j*4+3];
    gL[t] = g;
  }
  __syncthreads();
  const int grp = blockIdx.y * 4 + (t >> 6);
  const int lane = t & 63, l16 = lane & 15, quad = lane >> 4;
  const int e = grp * 16 + l16;
  const int ibase = i * (599 - i) / 2 - i - 1;   // p = ibase + j
  h8 outv;
  #pragma unroll
  for (int tt = 0; tt < 8; tt++) {
    int k = quad * 8 + tt;
    int j = j0 + k;
    float val = 0.f;
    if (j > i && j < 300 && e < 300)
      val = w7[(size_t)e * NPAIR + ibase + j] * gL[k];
    outv[tt] = (_Float16)val;
  }
  *(h8*)&Wgf[(((size_t)ch * 20 + grp) * 64 + lane) * 8] = outv;
}

// ---------- generic weight -> MFMA B-fragment order converter ----------
__global__ __launch_bounds__(256) void k_wf(
    const float* __restrict__ w, _Float16* __restrict__ Wf,
    int N, int K, int ngrp) {
  const int kt = blockIdx.x;
  const int grp = blockIdx.y * 4 + (threadIdx.x >> 6);
  const int lane = threadIdx.x & 63, l16 = lane & 15, quad = lane >> 4;
  const int e = grp * 16 + l16;
  if (grp >= ngrp) return;
  h8 o;
  #pragma unroll
  for (int tt = 0; tt < 8; tt++) {
    int k = kt * 32 + quad * 8 + tt;
    float val = (e < N && k < K) ? w[(size_t)e * K + k] : 0.f;
    o[tt] = (_Float16)val;
  }
  *(h8*)&Wf[(((size_t)kt * ngrp + grp) * 64 + lane) * 8] = o;
}

// ---------- attn fc: a[r][16] = relu(x[r] @ w^T + b), sabs[r] = sum|x[r]| ----------
__global__ __launch_bounds__(256) void k_attn2(
    const float* __restrict__ x, const float* __restrict__ w1, const float* __restrict__ b1,
    const float* __restrict__ w3, const float* __restrict__ b3,
    float* __restrict__ a, float* __restrict__ sabs) {
  __shared__ float xs[128][68];
  __shared__ float wL[16][308];
  const int tid = threadIdx.x;
  const int r0 = blockIdx.x * 128;
  for (int u = tid; u < 16 * 75; u += 256) {
    int t = u / 75, q = u - t * 75;
    float4 v4 = (t < 8) ? *(const float4*)&w1[t * 300 + q * 4]
                        : *(const float4*)&w3[(t - 8) * 300 + q * 4];
    *(float4*)&wL[t][q * 4] = v4;
  }
  const int rg = tid >> 3, tg = tid & 7;
  float acc[4][2] = {};
  float sa[4] = {};
  for (int k0 = 0; k0 < 300; k0 += 64) {
    int w = min(64, 300 - k0);
    __syncthreads();
    #pragma unroll
    for (int it = 0; it < 8; it++) {
      int u = tid + it * 256;
      int r = u >> 4, q = u & 15;
      float4 v4 = {0.f, 0.f, 0.f, 0.f};
      if (q * 4 < w) v4 = *(const float4*)&x[(size_t)(r0 + r) * 300 + k0 + q * 4];
      *(float4*)&xs[r][q * 4] = v4;
    }
    __syncthreads();
    for (int q = 0; q < (w >> 2); q++) {
      float4 w0 = *(float4*)&wL[tg * 2][k0 + q * 4];
      float4 w1v = *(float4*)&wL[tg * 2 + 1][k0 + q * 4];
      #pragma unroll
      for (int k2 = 0; k2 < 4; k2++) {
        float4 xv = *(float4*)&xs[rg + 32 * k2][q * 4];
        acc[k2][0] += xv.x * w0.x + xv.y * w0.y + xv.z * w0.z + xv.w * w0.w;
        acc[k2][1] += xv.x * w1v.x + xv.y * w1v.y + xv.z * w1v.z + xv.w * w1v.w;
        if (tg == 0)
          sa[k2] += fabsf(xv.x) + fabsf(xv.y) + fabsf(xv.z) + fabsf(xv.w);
      }
    }
  }
  int t0 = tg * 2;
  float bb0 = (t0 < 8) ? b1[t0] : b3[t0 - 8];
  float bb1 = (t0 + 1 < 8) ? b1[t0 + 1] : b3[t0 + 1 - 8];
  #pragma unroll
  for (int k2 = 0; k2 < 4; k2++) {
    size_t r = r0 + rg + 32 * k2;
    a[r * 16 + t0]     = fmaxf(acc[k2][0] + bb0, 0.f);
    a[r * 16 + t0 + 1] = fmaxf(acc[k2][1] + bb1, 0.f);
    if (tg == 0) sabs[r] = sa[k2];
  }
}

// ---------- attn BN stats over (B,T) per s ----------
__global__ void k_attnstats(const float* __restrict__ a, float* __restrict__ sstat) {
  int s = blockIdx.x, pool = blockIdx.y;
  float sum = 0.f, sq = 0.f;
  for (int b = threadIdx.x; b < B_; b += blockDim.x) {
    const float* row = &a[((size_t)b * S_ + s) * 16 + pool * 8];
    #pragma unroll
    for (int t = 0; t < 8; t++) { float v = row[t]; sum += v; sq += v * v; }
  }
  __shared__ float rs[2][4];
  int wave = threadIdx.x >> 6, lane = threadIdx.x & 63;
  #pragma unroll
  for (int off = 32; off; off >>= 1) { sum += __shfl_xor(sum, off); sq += __shfl_xor(sq, off); }
  if (lane == 0) { rs[0][wave] = sum; rs[1][wave] = sq; }
  __syncthreads();
  if (threadIdx.x == 0) {
    float S = rs[0][0] + rs[0][1] + rs[0][2] + rs[0][3];
    float Q = rs[1][0] + rs[1][1] + rs[1][2] + rs[1][3];
    float n = (float)(B_ * 8);
    float m = S / n;
    float var = Q / n - m * m;
    sstat[(pool * S_ + s) * 2 + 0] = m;
    sstat[(pool * S_ + s) * 2 + 1] = rsqrtf(var + 1e-5f);
  }
}

// ---------- scores + softmax + weighted pool -> hh f16 [B][608] (zero-padded) ----------
__global__ __launch_bounds__(256) void k_pool(
    const float* __restrict__ x, const float* __restrict__ a,
    const float* __restrict__ sabs, const float* __restrict__ sstat,
    const float* __restrict__ q1, const float* __restrict__ q2,
    _Float16* __restrict__ hh) {
  int b = blockIdx.x;
  __shared__ float w1s[S_], w2s[S_];
  int tid = threadIdx.x;
  if (tid < S_) {
    float sc1 = 0.f, sc2 = 0.f;
    const float* r1 = &a[((size_t)b * S_ + tid) * 16];
    const float* r2 = r1 + 8;
    float m1 = sstat[(0 * S_ + tid) * 2], rr1 = sstat[(0 * S_ + tid) * 2 + 1];
    float m2 = sstat[(1 * S_ + tid) * 2], rr2 = sstat[(1 * S_ + tid) * 2 + 1];
    #pragma unroll
    for (int t = 0; t < 8; t++) {
      sc1 += (r1[t] - m1) * rr1 * q1[t];
      sc2 += (r2[t] - m2) * rr2 * q2[t];
    }
    if (sabs[(size_t)b * S_ + tid] == 0.f) { sc1 = PADSCORE; sc2 = PADSCORE; }
    w1s[tid] = sc1; w2s[tid] = sc2;
  }
  __syncthreads();
  if (tid < 64) {
    float v1 = (tid < S_) ? w1s[tid] : -3.0e38f;
    float v2 = (tid < S_) ? w2s[tid] : -3.0e38f;
    float m1 = v1, m2 = v2;
    #pragma unroll
    for (int off = 32; off; off >>= 1) {
      m1 = fmaxf(m1, __shfl_xor(m1, off));
      m2 = fmaxf(m2, __shfl_xor(m2, off));
    }
    float e1 = (tid < S_) ? expf(v1 - m1) : 0.f;
    float e2 = (tid < S_) ? expf(v2 - m2) : 0.f;
    float s1 = e1, s2 = e2;
    #pragma unroll
    for (int off = 32; off; off >>= 1) { s1 += __shfl_xor(s1, off); s2 += __shfl_xor(s2, off); }
    if (tid < S_) { w1s[tid] = e1 / s1; w2s[tid] = e2 / s2; }
  }
  __syncthreads();
  for (int e = tid; e < E_; e += 256) {
    float p1 = 0.f, p2 = 0.f;
    for (int s = 0; s < S_; s++) {
      float xv = x[((size_t)b * S_ + s) * E_ + e];
      p1 += xv * w1s[s];
      p2 += xv * w2s[s];
    }
    hh[(size_t)b * 608 + e]       = (_Float16)p1;
    hh[(size_t)b * 608 + 300 + e] = (_Float16)p2;
  }
  if (tid < 8) hh[(size_t)b * 608 + 600 + tid] = (_Float16)0.f;
}

// ---------- f16 MFMA GEMM v2: no LDS, A-frags direct from global, dbl-buffered ----------
// Y = Xh @ Wf^T (frag-ordered W), fp32 out/partials.
// grid (M/64 mblk, nblkN, ksplit); block 256 = 4 waves (wm,wn 2x2); wave 32m x 80n.
// Requires Xh zero-padded so that nchunk*32 <= ldx and rows cover mblk*64+64.
__global__ __launch_bounds__(256) void k_gemmf(
    const _Float16* __restrict__ Xh, int ldx,
    const _Float16* __restrict__ Wf, int ngrp,
    float* __restrict__ dst, int N,
    int nchunk, int cps) {
  const int mblk = blockIdx.x, nblk = blockIdx.y, ks = blockIdx.z;
  const int tid = threadIdx.x;
  const int wave = tid >> 6, lane = tid & 63, quad = lane >> 4, l16 = lane & 15;
  const int wm = wave >> 1, wn = wave & 1;
  const int ck0 = ks * cps, ck1 = min(nchunk, ck0 + cps);

  f4 acc[2][5];
  #pragma unroll
  for (int i = 0; i < 2; i++)
    #pragma unroll
    for (int j = 0; j < 5; j++) acc[i][j] = (f4){0.f, 0.f, 0.f, 0.f};

  const int gbase = nblk * 10 + wn * 5;
  const _Float16* wb = Wf + ((size_t)gbase * 64 + lane) * 8;
  const _Float16* xb = Xh + (size_t)(mblk * 64 + wm * 32 + l16) * ldx + quad * 8;
  h8 aA[2], aB[2], bA[5], bB[5];
  #define LOADB(DST, CH)                                                        \
    _Pragma("unroll")                                                           \
    for (int nt = 0; nt < 5; nt++)                                              \
      DST[nt] = (gbase + nt < ngrp)                                             \
          ? *(const h8*)&wb[((size_t)(CH) * ngrp + nt) * 512]                   \
          : (h8){0, 0, 0, 0, 0, 0, 0, 0};
  #define LOADA(DST, CH)                                                        \
    _Pragma("unroll")                                                           \
    for (int mi = 0; mi < 2; mi++)                                              \
      DST[mi] = *(const h8*)&xb[(size_t)mi * 16 * ldx + (CH) * 32];

  if (ck0 < ck1) { LOADA(aA, ck0); LOADB(bA, ck0); }
  if (ck0 + 1 < ck1) { LOADA(aB, ck0 + 1); LOADB(bB, ck0 + 1); }

  auto step = [&](h8* af, h8* bf) {
    #pragma unroll
    for (int mi = 0; mi < 2; mi++)
      #pragma unroll
      for (int nt = 0; nt < 5; nt++)
        acc[mi][nt] = __builtin_amdgcn_mfma_f32_16x16x32_f16(af[mi], bf[nt], acc[mi][nt], 0, 0, 0);
  };

  int ch = ck0;
  while (ch < ck1) {
    step(aA, bA);
    if (ch + 2 < ck1) { LOADA(aA, ch + 2); LOADB(bA, ch + 2); }
    ch++;
    if (ch < ck1) {
      step(aB, bB);
      if (ch + 2 < ck1) { LOADA(aB, ch + 2); LOADB(bB, ch + 2); }
      ch++;
    }
  }
  #undef LOADB
  #undef LOADA

  float* d = dst + (size_t)ks * ((size_t)B_ * N);
  #pragma unroll
  for (int mi = 0; mi < 2; mi++) {
    int b = mblk * 64 + wm * 32 + mi * 16 + quad * 4;
    #pragma unroll
    for (int nt = 0; nt < 5; nt++) {
      int e = (gbase + nt) * 16 + l16;
      if (e < N) {
        #pragma unroll
        for (int r = 0; r < 4; r++)
          d[(size_t)(b + r) * N + e] = acc[mi][nt][r];
      }
    }
  }
}

// ---------- fused split-K reduce + column-stat partials (512 blocks x 4 rows) ----------
__global__ __launch_bounds__(256) void k_reduce_stat(
    const float* __restrict__ part, float* __restrict__ pre,
    float* __restrict__ cpart, int ksp) {
  int blk = blockIdx.x;              // RSBLK blocks x RSROWS rows
  int r0 = blk * RSROWS;
  for (int c = threadIdx.x; c < E_; c += 256) {
    float s = 0.f, q = 0.f;
    #pragma unroll
    for (int rr = 0; rr < RSROWS; rr++) {
      int r = r0 + rr;
      float v = 0.f;
      for (int k2 = 0; k2 < ksp; k2++)
        v += part[(size_t)k2 * (B_ * E_) + (size_t)r * E_ + c];
      pre[(size_t)r * E_ + c] = v;
      s += v; q += v * v;
    }
    cpart[((size_t)blk * E_ + c) * 2 + 0] = s;
    cpart[((size_t)blk * E_ + c) * 2 + 1] = q;
  }
}

// ---------- column-stat finalize (one block per column, tree reduce) ----------
__global__ __launch_bounds__(256) void k_colstat_fin(
    const float* __restrict__ part, float* __restrict__ stat,
    int N, int nparts, int M) {
  int c = blockIdx.x;
  if (c >= N) return;
  float s = 0.f, q = 0.f;
  for (int p = threadIdx.x; p < nparts; p += 256) {
    s += part[((size_t)p * N + c) * 2 + 0];
    q += part[((size_t)p * N + c) * 2 + 1];
  }
  #pragma unroll
  for (int off = 32; off; off >>= 1) { s += __shfl_xor(s, off); q += __shfl_xor(q, off); }
  __shared__ float rs[2][4];
  int wave = threadIdx.x >> 6, lane = threadIdx.x & 63;
  if (lane == 0) { rs[0][wave] = s; rs[1][wave] = q; }
  __syncthreads();
  if (threadIdx.x == 0) {
    float S = rs[0][0] + rs[0][1] + rs[0][2] + rs[0][3];
    float Q = rs[1][0] + rs[1][1] + rs[1][2] + rs[1][3];
    float m = S / (float)M;
    float var = Q / (float)M - m * m;
    stat[c * 2 + 0] = m;
    stat[c * 2 + 1] = rsqrtf(var + 1e-5f);
  }
}

// ---------- normalize -> h5h f16 [B][320] (zero-padded) ----------
__global__ void k_norm_h5h(const float* __restrict__ X, const float* __restrict__ stat,
                           _Float16* __restrict__ h5h) {
  int idx = blockIdx.x * 256 + threadIdx.x;
  if (idx >= B_ * 320) return;
  int b = idx / 320, c = idx - b * 320;
  if (c < E_) {
    float v = (X[(size_t)b * E_ + c] - stat[c * 2]) * stat[c * 2 + 1];
    h5h[idx] = (_Float16)v;
  } else {
    h5h[idx] = (_Float16)0.f;
  }
}

// ---------- normalize -> hcath f16 [B][608] at column offset (pad on off=300 pass) ----------
__global__ void k_norm_hcat(const float* __restrict__ X, const float* __restrict__ stat,
                            _Float16* __restrict__ Y, int off, int pad) {
  int W = 300 + pad;
  int idx = blockIdx.x * 256 + threadIdx.x;
  if (idx >= B_ * W) return;
  int b = idx / W, c = idx - b * W;
  if (c < 300) {
    float v = (X[(size_t)b * E_ + c] - stat[c * 2]) * stat[c * 2 + 1];
    Y[(size_t)b * 608 + off + c] = (_Float16)v;
  } else {
    Y[(size_t)b * 608 + 600 + (c - 300)] = (_Float16)0.f;
  }
}

// ---------- fc8 epilogue: reduce ksp partials + bias -> out8h f16 [B][320] ----------
__global__ void k_redbias_h(const float* __restrict__ part, const float* __restrict__ bias,
                            _Float16* __restrict__ out8h, int ksp) {
  int idx = blockIdx.x * 256 + threadIdx.x;
  if (idx >= B_ * 320) return;
  int b = idx / 320, c = idx - b * 320;
  if (c < E_) {
    float s = bias[c];
    for (int k2 = 0; k2 < ksp; k2++)
      s += part[(size_t)k2 * (B_ * E_) + (size_t)b * E_ + c];
    out8h[idx] = (_Float16)s;
  } else {
    out8h[idx] = (_Float16)0.f;
  }
}

// ---------- big MFMA GEMM v4 (unchanged, proven) ----------
__global__ __launch_bounds__(256, 3) void k_bigmm4(
    const _Float16* __restrict__ Wgf, const _Float16* __restrict__ h5h,
    const int* __restrict__ meta, float* __restrict__ part,
    int nchunks, int cps) {
  __shared__ _Float16 h5L[64][328];
  __shared__ int metaL[200];
  const int ks = blockIdx.x, mblk = blockIdx.y, nblk = blockIdx.z;
  const int tid = threadIdx.x;
  const int wave = tid >> 6, lane = tid & 63, quad = lane >> 4, l16 = lane & 15;
  const int wm = wave >> 1, wn = wave & 1;
  const int ch0 = ks * cps;
  const int ch1 = min(nchunks, ch0 + cps);
  {
    const _Float16* src = h5h + (size_t)mblk * 64 * 320;
    for (int u = tid; u < 64 * 41; u += 256) {
      int r = u / 41, c8 = u - r * 41;
      h8 v8 = {0, 0, 0, 0, 0, 0, 0, 0};
      if (c8 < 40) v8 = *(const h8*)&src[r * 320 + c8 * 8];
      *(h8*)&h5L[r][c8 * 8] = v8;
    }
    for (int u = tid; u < 200; u += 256)
      metaL[u] = (u < cps && ch0 + u < nchunks) ? meta[ch0 + u] : 0;
  }
  __syncthreads();

  f4 acc[2][5];
  #pragma unroll
  for (int i = 0; i < 2; i++)
    #pragma unroll
    for (int j = 0; j < 5; j++) acc[i][j] = (f4){0.f, 0.f, 0.f, 0.f};

  const _Float16* wbase = Wgf + ((size_t)(nblk * 10 + wn * 5) * 64 + lane) * 8;
  h8 bA[5], bB[5];
  #define LOADB(DST, CH)                                                       \
    _Pragma("unroll")                                                          \
    for (int nt = 0; nt < 5; nt++)                                             \
      DST[nt] = *(const h8*)&wbase[(size_t)(CH) * 10240 + nt * 512];

  if (ch0 < ch1) { LOADB(bA, ch0); }
  if (ch0 + 1 < ch1) { LOADB(bB, ch0 + 1); }

  _Float16 hi[2];
  int iiprev = -1;

  auto step = [&](int ch, h8* bf) {
    const int mt = metaL[ch - ch0];
    const int ii = mt & 0xffff, j0 = mt >> 16;
    if (ii != iiprev) {
      #pragma unroll
      for (int mi = 0; mi < 2; mi++) hi[mi] = h5L[wm * 32 + mi * 16 + l16][ii];
      iiprev = ii;
    }
    h8 af[2];
    #pragma unroll
    for (int mi = 0; mi < 2; mi++) {
      h8 vj = *(const h8*)&h5L[wm * 32 + mi * 16 + l16][j0 + quad * 8];
      _Float16 h = hi[mi];
      h8 hs = {h, h, h, h, h, h, h, h};
      af[mi] = vj * hs;
    }
    #pragma unroll
    for (int mi = 0; mi < 2; mi++)
      #pragma unroll
      for (int nt = 0; nt < 5; nt++)
        acc[mi][nt] = __builtin_amdgcn_mfma_f32_16x16x32_f16(af[mi], bf[nt], acc[mi][nt], 0, 0, 0);
  };

  int ch = ch0;
  while (ch < ch1) {
    step(ch, bA);
    if (ch + 2 < ch1) { LOADB(bA, ch + 2); }
    ch++;
    if (ch < ch1) {
      step(ch, bB);
      if (ch + 2 < ch1) { LOADB(bB, ch + 2); }
      ch++;
    }
  }
  #undef LOADB

  float* dst = part + (size_t)ks * (B_ * E_);
  #pragma unroll
  for (int mi = 0; mi < 2; mi++) {
    int b = mblk * 64 + wm * 32 + mi * 16 + quad * 4;
    #pragma unroll
    for (int nt = 0; nt < 5; nt++) {
      int e = nblk * 160 + wn * 80 + nt * 16 + l16;
      if (e < E_) {
        #pragma unroll
        for (int r = 0; r < 4; r++)
          dst[(size_t)(b + r) * E_ + e] = acc[mi][nt][r];
      }
    }
  }
}

extern "C" void kernel_launch(void* const* d_in, const int* in_sizes, int n_in,
                              void* d_out, int out_size, void* d_ws, size_t ws_size,
                              hipStream_t stream) {
  const float* x    = (const float*)d_in[0];
  const float* lemb = (const float*)d_in[1];
  const float* fc1w = (const float*)d_in[2];
  const float* fc1b = (const float*)d_in[3];
  const float* q1   = (const float*)d_in[4];
  const float* fc3w = (const float*)d_in[5];
  const float* fc3b = (const float*)d_in[6];
  const float* q2   = (const float*)d_in[7];
  const float* fc5w = (const float*)d_in[8];
  const float* fc6w = (const float*)d_in[10];
  const float* fc7w = (const float*)d_in[12];
  const float* fc8w = (const float*)d_in[14];
  const float* fc8b = (const float*)d_in[15];
  const float* v    = (const float*)d_in[16];
  float* out = (float*)d_out;
  (void)in_sizes; (void)n_in; (void)out_size; (void)ws_size;

  // chunk enumeration (host-side): nchunks = 1586
  int nchunks = 0;
  for (int i = 0; i < 299; i++) { int js = (i + 1) & ~7; nchunks += (300 - js + 31) >> 5; }
  int cps = (nchunks + KSPLIT - 1) / KSPLIT;   // 133 @ KSPLIT=12

  char* base = (char*)d_ws;
  size_t off = 0;
  auto alloc = [&](size_t nbytes) -> char* {
    char* p = base + off;
    off = (off + nbytes + 255) & ~(size_t)255;
    return p;
  };
  int*       meta  = (int*)      alloc((size_t)nchunks * 4);
  _Float16*  Wgf   = (_Float16*) alloc((size_t)nchunks * 20 * 64 * 8 * 2);  // 32.5 MB
  _Float16*  Wf5   = (_Float16*) alloc((size_t)19 * 19 * 512 * 2);
  _Float16*  Wf6   = (_Float16*) alloc((size_t)10 * 19 * 512 * 2);
  _Float16*  Wf8   = (_Float16*) alloc((size_t)19 * 19 * 512 * 2);
  _Float16*  WfL   = (_Float16*) alloc((size_t)10 * 63 * 512 * 2);
  _Float16*  hh    = (_Float16*) alloc((size_t)B_ * 608 * 2);
  _Float16*  h5h   = (_Float16*) alloc((size_t)B_ * 320 * 2);
  _Float16*  hcath = (_Float16*) alloc((size_t)B_ * 608 * 2);
  _Float16*  out8h = (_Float16*) alloc((size_t)B_ * 320 * 2);
  float*     pre   = (float*)    alloc((size_t)B_ * E_ * 4);   // shared h5pre/h6pre/h7pre
  float*     cpart = (float*)    alloc((size_t)RSBLK * E_ * 2 * 4);  // 1.23 MB
  float*     cstat = (float*)    alloc((size_t)E_ * 2 * 4);
  size_t part_bytes = (size_t)KSPLIT * B_ * E_ * 4;            // 29.5 MB
  char* scratch = alloc(part_bytes);
  float* a     = (float*)scratch;                              // [R_][16] 6.55 MB (phase 1)
  float* sabs  = a + (size_t)R_ * 16;
  float* sstat = sabs + R_;
  float* part  = (float*)scratch;                              // reused after k_pool

  // prep: metadata + all weight conversions
  hipLaunchKernelGGL(k_meta, dim3(1), dim3(320), 0, stream, meta);
  hipLaunchKernelGGL(k_wg3, dim3(nchunks, 5), dim3(256), 0, stream, fc7w, v, meta, Wgf);
  hipLaunchKernelGGL(k_wf, dim3(19, 5), dim3(256), 0, stream, fc5w, Wf5, 300, 600, 19);
  hipLaunchKernelGGL(k_wf, dim3(10, 5), dim3(256), 0, stream, fc6w, Wf6, 300, 300, 19);
  hipLaunchKernelGGL(k_wf, dim3(19, 5), dim3(256), 0, stream, fc8w, Wf8, 300, 600, 19);
  hipLaunchKernelGGL(k_wf, dim3(10, 16), dim3(256), 0, stream, lemb, WfL, 1000, 300, 63);
  // attention pools
  hipLaunchKernelGGL(k_attn2, dim3(R_ / 128), dim3(256), 0, stream, x, fc1w, fc1b, fc3w, fc3b, a, sabs);
  hipLaunchKernelGGL(k_attnstats, dim3(S_, 2), dim3(256), 0, stream, a, sstat);
  hipLaunchKernelGGL(k_pool, dim3(B_), dim3(256), 0, stream, x, a, sabs, sstat, q1, q2, hh);
  // fc5 (f16 MFMA, ksplit 8) + BN -> h5h
  hipLaunchKernelGGL(k_gemmf, dim3(32, 2, 8), dim3(256), 0, stream, hh, 608, Wf5, 19, part, 300, 19, 3);
  hipLaunchKernelGGL(k_reduce_stat, dim3(RSBLK), dim3(256), 0, stream, part, pre, cpart, 8);
  hipLaunchKernelGGL(k_colstat_fin, dim3(E_), dim3(256), 0, stream, cpart, cstat, E_, RSBLK, B_);
  hipLaunchKernelGGL(k_norm_h5h, dim3((B_ * 320) / 256), dim3(256), 0, stream, pre, cstat, h5h);
  // fc6 + BN -> hcath[:, :300]
  hipLaunchKernelGGL(k_gemmf, dim3(32, 2, 8), dim3(256), 0, stream, h5h, 320, Wf6, 19, part, 300, 10, 2);
  hipLaunchKernelGGL(k_reduce_stat, dim3(RSBLK), dim3(256), 0, stream, part, pre, cpart, 8);
  hipLaunchKernelGGL(k_colstat_fin, dim3(E_), dim3(256), 0, stream, cpart, cstat, E_, RSBLK, B_);
  hipLaunchKernelGGL(k_norm_hcat, dim3((B_ * 300 + 255) / 256), dim3(256), 0, stream, pre, cstat, hcath, 0, 0);
  // cross-feature GEMM + BN -> hcath[:, 300:] (+pad)
  hipLaunchKernelGGL(k_bigmm4, dim3(KSPLIT, 32, 2), dim3(256), 0, stream, Wgf, h5h, meta, part, nchunks, cps);
  hipLaunchKernelGGL(k_reduce_stat, dim3(RSBLK), dim3(256), 0, stream, part, pre, cpart, KSPLIT);
  hipLaunchKernelGGL(k_colstat_fin, dim3(E_), dim3(256), 0, stream, cpart, cstat, E_, RSBLK, B_);
  hipLaunchKernelGGL(k_norm_hcat, dim3((B_ * 308 + 255) / 256), dim3(256), 0, stream, pre, cstat, hcath, 300, 8);
  // fc8 (ksplit 8) + bias -> out8h f16
  hipLaunchKernelGGL(k_gemmf, dim3(32, 2, 8), dim3(256), 0, stream, hcath, 608, Wf8, 19, part, 300, 19, 3);
  hipLaunchKernelGGL(k_redbias_h, dim3((B_ * 320) / 256), dim3(256), 0, stream, part, fc8b, out8h, 8);
  // label projection (direct f32 out)
  hipLaunchKernelGGL(k_gemmf, dim3(32, 7, 1), dim3(256), 0, stream, out8h, 320, WfL, 63, out, 1000, 10, 10);
}

// Round 3
// 525.951 us; speedup vs baseline: 1.0319x; 1.0319x over previous
//
#include <hip/hip_runtime.h>

#define B_ 2048
#define S_ 50
#define E_ 300
#define NPAIR 44850
#define R_ (B_ * S_)            // 102400 rows for attn fc
#define PADSCORE (-4294967295.0f)
#define RSBLK 512               // blocks for k_reduce_stat (4 rows each)
#define RSROWS (B_ / RSBLK)

// ---- c-major padded chunk schedule for the cross-feature GEMM ----
// c-block c (cols [32c,32c+32)): i runs 0..Lc-1, Lc = min(299,32c+31) padded to x8.
// Lc = 32(c+1) for c<=8, 304 for c=9. cum(c) = 16*c*(c+1); NPOS = 1744.
#define NPOS 1744
#define BKSPLIT 16
#define BCPS 112                // pos per ks slice, multiple of 8; 16*112 >= 1744

typedef _Float16 h8 __attribute__((ext_vector_type(8)));
typedef float f4 __attribute__((ext_vector_type(4)));

// ---------- chunk metadata (c-major): meta[pos] = i | (j0<<16), j0 = 32c ----------
__global__ void k_meta(int* __restrict__ meta) {
  int pos = blockIdx.x * 256 + threadIdx.x;
  if (pos >= NPOS) return;
  int c = 0;
  #pragma unroll
  for (int cc = 1; cc < 10; cc++) if (pos >= 16 * cc * (cc + 1)) c = cc;
  meta[pos] = (pos - 16 * c * (c + 1)) | ((c * 32) << 16);
}

// ---------- Wgf in MFMA B-fragment order (cross-feature weights * g) ----------
// Padded chunks (i beyond real range) produce all-zero B via the j>i mask.
__global__ __launch_bounds__(256) void k_wg3(
    const float* __restrict__ w7, const float* __restrict__ v,
    const int* __restrict__ meta, _Float16* __restrict__ Wgf) {
  __shared__ float gL[32];
  const int ch = blockIdx.x;
  const int mt = meta[ch];
  const int i = mt & 0xffff, j0 = mt >> 16;
  const int t = threadIdx.x;
  if (t < 32) {
    int j = j0 + t;
    float g = 0.f;
    if (j > i && j < 300)
      g = v[i*4+0]*v[j*4+0] + v[i*4+1]*v[j*4+1] + v[i*4+2]*v[j*4+2] + v[i*4+3]*v[j*4+3];
    gL[t] = g;
  }
  __syncthreads();
  const int grp = blockIdx.y * 4 + (t >> 6);
  const int lane = t & 63, l16 = lane & 15, quad = lane >> 4;
  const int e = grp * 16 + l16;
  const int ibase = i * (599 - i) / 2 - i - 1;   // p = ibase + j
  h8 outv;
  #pragma unroll
  for (int tt = 0; tt < 8; tt++) {
    int k = quad * 8 + tt;
    int j = j0 + k;
    float val = 0.f;
    if (j > i && j < 300 && e < 300)
      val = w7[(size_t)e * NPAIR + ibase + j] * gL[k];
    outv[tt] = (_Float16)val;
  }
  *(h8*)&Wgf[(((size_t)ch * 20 + grp) * 64 + lane) * 8] = outv;
}

// ---------- generic weight -> MFMA B-fragment order converter ----------
__global__ __launch_bounds__(256) void k_wf(
    const float* __restrict__ w, _Float16* __restrict__ Wf,
    int N, int K, int ngrp) {
  const int kt = blockIdx.x;
  const int grp = blockIdx.y * 4 + (threadIdx.x >> 6);
  const int lane = threadIdx.x & 63, l16 = lane & 15, quad = lane >> 4;
  const int e = grp * 16 + l16;
  if (grp >= ngrp) return;
  h8 o;
  #pragma unroll
  for (int tt = 0; tt < 8; tt++) {
    int k = kt * 32 + quad * 8 + tt;
    float val = (e < N && k < K) ? w[(size_t)e * K + k] : 0.f;
    o[tt] = (_Float16)val;
  }
  *(h8*)&Wf[(((size_t)kt * ngrp + grp) * 64 + lane) * 8] = o;
}

// ---------- attn fc: a[r][16] = relu(x[r] @ w^T + b), sabs[r] = sum|x[r]| ----------
__global__ __launch_bounds__(256) void k_attn2(
    const float* __restrict__ x, const float* __restrict__ w1, const float* __restrict__ b1,
    const float* __restrict__ w3, const float* __restrict__ b3,
    float* __restrict__ a, float* __restrict__ sabs) {
  __shared__ float xs[128][68];
  __shared__ float wL[16][308];
  const int tid = threadIdx.x;
  const int r0 = blockIdx.x * 128;
  for (int u = tid; u < 16 * 75; u += 256) {
    int t = u / 75, q = u - t * 75;
    float4 v4 = (t < 8) ? *(const float4*)&w1[t * 300 + q * 4]
                        : *(const float4*)&w3[(t - 8) * 300 + q * 4];
    *(float4*)&wL[t][q * 4] = v4;
  }
  const int rg = tid >> 3, tg = tid & 7;
  float acc[4][2] = {};
  float sa[4] = {};
  for (int k0 = 0; k0 < 300; k0 += 64) {
    int w = min(64, 300 - k0);
    __syncthreads();
    #pragma unroll
    for (int it = 0; it < 8; it++) {
      int u = tid + it * 256;
      int r = u >> 4, q = u & 15;
      float4 v4 = {0.f, 0.f, 0.f, 0.f};
      if (q * 4 < w) v4 = *(const float4*)&x[(size_t)(r0 + r) * 300 + k0 + q * 4];
      *(float4*)&xs[r][q * 4] = v4;
    }
    __syncthreads();
    for (int q = 0; q < (w >> 2); q++) {
      float4 w0 = *(float4*)&wL[tg * 2][k0 + q * 4];
      float4 w1v = *(float4*)&wL[tg * 2 + 1][k0 + q * 4];
      #pragma unroll
      for (int k2 = 0; k2 < 4; k2++) {
        float4 xv = *(float4*)&xs[rg + 32 * k2][q * 4];
        acc[k2][0] += xv.x * w0.x + xv.y * w0.y + xv.z * w0.z + xv.w * w0.w;
        acc[k2][1] += xv.x * w1v.x + xv.y * w1v.y + xv.z * w1v.z + xv.w * w1v.w;
        if (tg == 0)
          sa[k2] += fabsf(xv.x) + fabsf(xv.y) + fabsf(xv.z) + fabsf(xv.w);
      }
    }
  }
  int t0 = tg * 2;
  float bb0 = (t0 < 8) ? b1[t0] : b3[t0 - 8];
  float bb1 = (t0 + 1 < 8) ? b1[t0 + 1] : b3[t0 + 1 - 8];
  #pragma unroll
  for (int k2 = 0; k2 < 4; k2++) {
    size_t r = r0 + rg + 32 * k2;
    a[r * 16 + t0]     = fmaxf(acc[k2][0] + bb0, 0.f);
    a[r * 16 + t0 + 1] = fmaxf(acc[k2][1] + bb1, 0.f);
    if (tg == 0) sabs[r] = sa[k2];
  }
}

// ---------- attn BN stats over (B,T) per s ----------
__global__ void k_attnstats(const float* __restrict__ a, float* __restrict__ sstat) {
  int s = blockIdx.x, pool = blockIdx.y;
  float sum = 0.f, sq = 0.f;
  for (int b = threadIdx.x; b < B_; b += blockDim.x) {
    const float* row = &a[((size_t)b * S_ + s) * 16 + pool * 8];
    #pragma unroll
    for (int t = 0; t < 8; t++) { float v = row[t]; sum += v; sq += v * v; }
  }
  __shared__ float rs[2][4];
  int wave = threadIdx.x >> 6, lane = threadIdx.x & 63;
  #pragma unroll
  for (int off = 32; off; off >>= 1) { sum += __shfl_xor(sum, off); sq += __shfl_xor(sq, off); }
  if (lane == 0) { rs[0][wave] = sum; rs[1][wave] = sq; }
  __syncthreads();
  if (threadIdx.x == 0) {
    float S = rs[0][0] + rs[0][1] + rs[0][2] + rs[0][3];
    float Q = rs[1][0] + rs[1][1] + rs[1][2] + rs[1][3];
    float n = (float)(B_ * 8);
    float m = S / n;
    float var = Q / n - m * m;
    sstat[(pool * S_ + s) * 2 + 0] = m;
    sstat[(pool * S_ + s) * 2 + 1] = rsqrtf(var + 1e-5f);
  }
}

// ---------- scores + softmax + weighted pool -> hh f16 [B][608] (zero-padded) ----------
__global__ __launch_bounds__(256) void k_pool(
    const float* __restrict__ x, const float* __restrict__ a,
    const float* __restrict__ sabs, const float* __restrict__ sstat,
    const float* __restrict__ q1, const float* __restrict__ q2,
    _Float16* __restrict__ hh) {
  int b = blockIdx.x;
  __shared__ float w1s[S_], w2s[S_];
  int tid = threadIdx.x;
  if (tid < S_) {
    float sc1 = 0.f, sc2 = 0.f;
    const float* r1 = &a[((size_t)b * S_ + tid) * 16];
    const float* r2 = r1 + 8;
    float m1 = sstat[(0 * S_ + tid) * 2], rr1 = sstat[(0 * S_ + tid) * 2 + 1];
    float m2 = sstat[(1 * S_ + tid) * 2], rr2 = sstat[(1 * S_ + tid) * 2 + 1];
    #pragma unroll
    for (int t = 0; t < 8; t++) {
      sc1 += (r1[t] - m1) * rr1 * q1[t];
      sc2 += (r2[t] - m2) * rr2 * q2[t];
    }
    if (sabs[(size_t)b * S_ + tid] == 0.f) { sc1 = PADSCORE; sc2 = PADSCORE; }
    w1s[tid] = sc1; w2s[tid] = sc2;
  }
  __syncthreads();
  if (tid < 64) {
    float v1 = (tid < S_) ? w1s[tid] : -3.0e38f;
    float v2 = (tid < S_) ? w2s[tid] : -3.0e38f;
    float m1 = v1, m2 = v2;
    #pragma unroll
    for (int off = 32; off; off >>= 1) {
      m1 = fmaxf(m1, __shfl_xor(m1, off));
      m2 = fmaxf(m2, __shfl_xor(m2, off));
    }
    float e1 = (tid < S_) ? expf(v1 - m1) : 0.f;
    float e2 = (tid < S_) ? expf(v2 - m2) : 0.f;
    float s1 = e1, s2 = e2;
    #pragma unroll
    for (int off = 32; off; off >>= 1) { s1 += __shfl_xor(s1, off); s2 += __shfl_xor(s2, off); }
    if (tid < S_) { w1s[tid] = e1 / s1; w2s[tid] = e2 / s2; }
  }
  __syncthreads();
  for (int e = tid; e < E_; e += 256) {
    float p1 = 0.f, p2 = 0.f;
    for (int s = 0; s < S_; s++) {
      float xv = x[((size_t)b * S_ + s) * E_ + e];
      p1 += xv * w1s[s];
      p2 += xv * w2s[s];
    }
    hh[(size_t)b * 608 + e]       = (_Float16)p1;
    hh[(size_t)b * 608 + 300 + e] = (_Float16)p2;
  }
  if (tid < 8) hh[(size_t)b * 608 + 600 + tid] = (_Float16)0.f;
}

// ---------- f16 MFMA GEMM (round-1 proven LDS version) ----------
__global__ __launch_bounds__(256) void k_gemmf(
    const _Float16* __restrict__ Xh, int ldx,
    const _Float16* __restrict__ Wf, int ngrp,
    float* __restrict__ dst, int N,
    int nchunk, int cps) {
  __shared__ _Float16 XL[64][328];
  const int mblk = blockIdx.x, nblk = blockIdx.y, ks = blockIdx.z;
  const int tid = threadIdx.x;
  const int wave = tid >> 6, lane = tid & 63, quad = lane >> 4, l16 = lane & 15;
  const int wm = wave >> 1, wn = wave & 1;
  const int ck0 = ks * cps, ck1 = min(nchunk, ck0 + cps);
  const int ncol8 = (ck1 - ck0) * 4;
  {
    const _Float16* src = Xh + (size_t)mblk * 64 * ldx + ck0 * 32;
    for (int u = tid; u < 64 * ncol8; u += 256) {
      int r = u / ncol8, c8 = u - r * ncol8;
      *(h8*)&XL[r][c8 * 8] = *(const h8*)&src[(size_t)r * ldx + c8 * 8];
    }
  }
  __syncthreads();

  f4 acc[2][5];
  #pragma unroll
  for (int i = 0; i < 2; i++)
    #pragma unroll
    for (int j = 0; j < 5; j++) acc[i][j] = (f4){0.f, 0.f, 0.f, 0.f};

  const int gbase = nblk * 10 + wn * 5;
  const _Float16* wb = Wf + ((size_t)gbase * 64 + lane) * 8;
  h8 bA[5], bB[5];
  #define LOADB(DST, CH)                                                        \
    _Pragma("unroll")                                                           \
    for (int nt = 0; nt < 5; nt++)                                              \
      DST[nt] = (gbase + nt < ngrp)                                             \
          ? *(const h8*)&wb[((size_t)(CH) * ngrp + nt) * 512]                   \
          : (h8){0, 0, 0, 0, 0, 0, 0, 0};

  if (ck0 < ck1) { LOADB(bA, ck0); }
  if (ck0 + 1 < ck1) { LOADB(bB, ck0 + 1); }

  auto step = [&](int ch, h8* bf) {
    int c0 = (ch - ck0) * 32 + quad * 8;
    h8 af[2];
    #pragma unroll
    for (int mi = 0; mi < 2; mi++)
      af[mi] = *(const h8*)&XL[wm * 32 + mi * 16 + l16][c0];
    #pragma unroll
    for (int mi = 0; mi < 2; mi++)
      #pragma unroll
      for (int nt = 0; nt < 5; nt++)
        acc[mi][nt] = __builtin_amdgcn_mfma_f32_16x16x32_f16(af[mi], bf[nt], acc[mi][nt], 0, 0, 0);
  };

  int ch = ck0;
  while (ch < ck1) {
    step(ch, bA);
    if (ch + 2 < ck1) { LOADB(bA, ch + 2); }
    ch++;
    if (ch < ck1) {
      step(ch, bB);
      if (ch + 2 < ck1) { LOADB(bB, ch + 2); }
      ch++;
    }
  }
  #undef LOADB

  float* d = dst + (size_t)ks * ((size_t)B_ * N);
  #pragma unroll
  for (int mi = 0; mi < 2; mi++) {
    int b = mblk * 64 + wm * 32 + mi * 16 + quad * 4;
    #pragma unroll
    for (int nt = 0; nt < 5; nt++) {
      int e = (gbase + nt) * 16 + l16;
      if (e < N) {
        #pragma unroll
        for (int r = 0; r < 4; r++)
          d[(size_t)(b + r) * N + e] = acc[mi][nt][r];
      }
    }
  }
}

// ---------- fused split-K reduce + column-stat partials (512 blocks x 4 rows) ----------
__global__ __launch_bounds__(256) void k_reduce_stat(
    const float* __restrict__ part, float* __restrict__ pre,
    float* __restrict__ cpart, int ksp) {
  int blk = blockIdx.x;              // RSBLK blocks x RSROWS rows
  int r0 = blk * RSROWS;
  for (int c = threadIdx.x; c < E_; c += 256) {
    float s = 0.f, q = 0.f;
    #pragma unroll
    for (int rr = 0; rr < RSROWS; rr++) {
      int r = r0 + rr;
      float v = 0.f;
      for (int k2 = 0; k2 < ksp; k2++)
        v += part[(size_t)k2 * (B_ * E_) + (size_t)r * E_ + c];
      pre[(size_t)r * E_ + c] = v;
      s += v; q += v * v;
    }
    cpart[((size_t)blk * E_ + c) * 2 + 0] = s;
    cpart[((size_t)blk * E_ + c) * 2 + 1] = q;
  }
}

// ---------- column-stat finalize (one block per column, tree reduce) ----------
__global__ __launch_bounds__(256) void k_colstat_fin(
    const float* __restrict__ part, float* __restrict__ stat,
    int N, int nparts, int M) {
  int c = blockIdx.x;
  if (c >= N) return;
  float s = 0.f, q = 0.f;
  for (int p = threadIdx.x; p < nparts; p += 256) {
    s += part[((size_t)p * N + c) * 2 + 0];
    q += part[((size_t)p * N + c) * 2 + 1];
  }
  #pragma unroll
  for (int off = 32; off; off >>= 1) { s += __shfl_xor(s, off); q += __shfl_xor(q, off); }
  __shared__ float rs[2][4];
  int wave = threadIdx.x >> 6, lane = threadIdx.x & 63;
  if (lane == 0) { rs[0][wave] = s; rs[1][wave] = q; }
  __syncthreads();
  if (threadIdx.x == 0) {
    float S = rs[0][0] + rs[0][1] + rs[0][2] + rs[0][3];
    float Q = rs[1][0] + rs[1][1] + rs[1][2] + rs[1][3];
    float m = S / (float)M;
    float var = Q / (float)M - m * m;
    stat[c * 2 + 0] = m;
    stat[c * 2 + 1] = rsqrtf(var + 1e-5f);
  }
}

// ---------- normalize -> h5h f16 [B][320] (zero-padded) ----------
__global__ void k_norm_h5h(const float* __restrict__ X, const float* __restrict__ stat,
                           _Float16* __restrict__ h5h) {
  int idx = blockIdx.x * 256 + threadIdx.x;
  if (idx >= B_ * 320) return;
  int b = idx / 320, c = idx - b * 320;
  if (c < E_) {
    float v = (X[(size_t)b * E_ + c] - stat[c * 2]) * stat[c * 2 + 1];
    h5h[idx] = (_Float16)v;
  } else {
    h5h[idx] = (_Float16)0.f;
  }
}

// ---------- normalize -> hcath f16 [B][608] at column offset (pad on off=300 pass) ----------
__global__ void k_norm_hcat(const float* __restrict__ X, const float* __restrict__ stat,
                            _Float16* __restrict__ Y, int off, int pad) {
  int W = 300 + pad;
  int idx = blockIdx.x * 256 + threadIdx.x;
  if (idx >= B_ * W) return;
  int b = idx / W, c = idx - b * W;
  if (c < 300) {
    float v = (X[(size_t)b * E_ + c] - stat[c * 2]) * stat[c * 2 + 1];
    Y[(size_t)b * 608 + off + c] = (_Float16)v;
  } else {
    Y[(size_t)b * 608 + 600 + (c - 300)] = (_Float16)0.f;
  }
}

// ---------- fc8 epilogue: reduce ksp partials + bias -> out8h f16 [B][320] ----------
__global__ void k_redbias_h(const float* __restrict__ part, const float* __restrict__ bias,
                            _Float16* __restrict__ out8h, int ksp) {
  int idx = blockIdx.x * 256 + threadIdx.x;
  if (idx >= B_ * 320) return;
  int b = idx / 320, c = idx - b * 320;
  if (c < E_) {
    float s = bias[c];
    for (int k2 = 0; k2 < ksp; k2++)
      s += part[(size_t)k2 * (B_ * E_) + (size_t)b * E_ + c];
    out8h[idx] = (_Float16)s;
  } else {
    out8h[idx] = (_Float16)0.f;
  }
}

// ---------- big MFMA GEMM v5: c-major schedule, register A-side, no LDS ----------
// Per c-block: vj (A k-vector) is loop-invariant; only scalar h_i changes per step.
// M-tile 128 (mi=4), halves B traffic vs v4. 1-D grid 512 = 2 blocks/CU;
// blocks of one (ks,nblk) group are id%32-equal -> same XCD (id%8), so each
// XCD L2 caches 4 B-slices (~2.3 MB) and serves them at full rate.
__global__ __launch_bounds__(256, 2) void k_bigmm5(
    const _Float16* __restrict__ Wgf, const _Float16* __restrict__ h5h,
    float* __restrict__ part) {
  const int n = blockIdx.x;
  const int g = n & 31, mblk = n >> 5;
  const int ks = g >> 1, nblk = g & 1;
  const int tid = threadIdx.x;
  const int wave = tid >> 6, lane = tid & 63, quad = lane >> 4, l16 = lane & 15;
  const int wm = wave >> 1, wn = wave & 1;
  const int pos0 = ks * BCPS;
  const int pos1 = min(NPOS, pos0 + BCPS);

  const int gbase = nblk * 10 + wn * 5;
  const _Float16* wb = Wgf + ((size_t)gbase * 64 + lane) * 8;

  const _Float16* rowp[4];
  #pragma unroll
  for (int mi = 0; mi < 4; mi++)
    rowp[mi] = h5h + (size_t)(mblk * 128 + wm * 64 + mi * 16 + l16) * 320;

  f4 acc[4][5];
  #pragma unroll
  for (int i = 0; i < 4; i++)
    #pragma unroll
    for (int j = 0; j < 5; j++) acc[i][j] = (f4){0.f, 0.f, 0.f, 0.f};

  h8 bA[5], bB[5], vj[4];

  #define LOADB5(DST, POS)                                                     \
    _Pragma("unroll")                                                          \
    for (int nt = 0; nt < 5; nt++)                                             \
      DST[nt] = *(const h8*)&wb[(size_t)(POS) * 10240 + nt * 512];

  // initial c-block for pos0 (cum(c) = 16*c*(c+1); boundaries are x32-aligned)
  int c = 0, cend = 32;
  while (pos0 >= cend) { c++; cend = (c < 9) ? 16 * (c + 1) * (c + 2) : NPOS; }
  int cumc = 16 * c * (c + 1);
  #pragma unroll
  for (int mi = 0; mi < 4; mi++)
    vj[mi] = *(const h8*)&rowp[mi][c * 32 + quad * 8];

  LOADB5(bA, pos0);
  LOADB5(bB, pos0 + 1);

  #define STEP5(BUF, T)                                                        \
    _Pragma("unroll")                                                          \
    for (int mi = 0; mi < 4; mi++) {                                           \
      _Float16 hsc = hi8[mi][T];                                               \
      h8 hs = {hsc, hsc, hsc, hsc, hsc, hsc, hsc, hsc};                        \
      h8 af = vj[mi] * hs;                                                     \
      _Pragma("unroll")                                                        \
      for (int nt = 0; nt < 5; nt++)                                           \
        acc[mi][nt] = __builtin_amdgcn_mfma_f32_16x16x32_f16(af, BUF[nt], acc[mi][nt], 0, 0, 0); \
    }

  for (int p = pos0; p < pos1; p += 8) {
    if (p >= cend) {
      do { c++; cend = (c < 9) ? 16 * (c + 1) * (c + 2) : NPOS; } while (p >= cend);
      cumc = 16 * c * (c + 1);
      #pragma unroll
      for (int mi = 0; mi < 4; mi++)
        vj[mi] = *(const h8*)&rowp[mi][c * 32 + quad * 8];
    }
    const int i0 = p - cumc;          // x8-aligned within c-block
    h8 hi8[4];
    #pragma unroll
    for (int mi = 0; mi < 4; mi++)
      hi8[mi] = *(const h8*)&rowp[mi][i0];

    #pragma unroll
    for (int t = 0; t < 8; t += 2) {
      STEP5(bA, t);     LOADB5(bA, p + t + 2);
      STEP5(bB, t + 1); LOADB5(bB, p + t + 3);
    }
  }
  #undef LOADB5
  #undef STEP5

  float* dst = part + (size_t)ks * (B_ * E_);
  const int b0 = mblk * 128 + wm * 64;
  #pragma unroll
  for (int mi = 0; mi < 4; mi++) {
    int b = b0 + mi * 16 + quad * 4;
    #pragma unroll
    for (int nt = 0; nt < 5; nt++) {
      int e = (gbase + nt) * 16 + l16;
      if (e < E_) {
        #pragma unroll
        for (int r = 0; r < 4; r++)
          dst[(size_t)(b + r) * E_ + e] = acc[mi][nt][r];
      }
    }
  }
}

extern "C" void kernel_launch(void* const* d_in, const int* in_sizes, int n_in,
                              void* d_out, int out_size, void* d_ws, size_t ws_size,
                              hipStream_t stream) {
  const float* x    = (const float*)d_in[0];
  const float* lemb = (const float*)d_in[1];
  const float* fc1w = (const float*)d_in[2];
  const float* fc1b = (const float*)d_in[3];
  const float* q1   = (const float*)d_in[4];
  const float* fc3w = (const float*)d_in[5];
  const float* fc3b = (const float*)d_in[6];
  const float* q2   = (const float*)d_in[7];
  const float* fc5w = (const float*)d_in[8];
  const float* fc6w = (const float*)d_in[10];
  const float* fc7w = (const float*)d_in[12];
  const float* fc8w = (const float*)d_in[14];
  const float* fc8b = (const float*)d_in[15];
  const float* v    = (const float*)d_in[16];
  float* out = (float*)d_out;
  (void)in_sizes; (void)n_in; (void)out_size; (void)ws_size;

  char* base = (char*)d_ws;
  size_t off = 0;
  auto alloc = [&](size_t nbytes) -> char* {
    char* p = base + off;
    off = (off + nbytes + 255) & ~(size_t)255;
    return p;
  };
  int*       meta  = (int*)      alloc((size_t)NPOS * 4);
  _Float16*  Wgf   = (_Float16*) alloc((size_t)(NPOS + 8) * 20 * 64 * 8 * 2);  // 35.9 MB (+slack for prefetch overrun)
  _Float16*  Wf5   = (_Float16*) alloc((size_t)19 * 19 * 512 * 2);
  _Float16*  Wf6   = (_Float16*) alloc((size_t)10 * 19 * 512 * 2);
  _Float16*  Wf8   = (_Float16*) alloc((size_t)19 * 19 * 512 * 2);
  _Float16*  WfL   = (_Float16*) alloc((size_t)10 * 63 * 512 * 2);
  _Float16*  hh    = (_Float16*) alloc((size_t)B_ * 608 * 2);
  _Float16*  h5h   = (_Float16*) alloc((size_t)B_ * 320 * 2);
  _Float16*  hcath = (_Float16*) alloc((size_t)B_ * 608 * 2);
  _Float16*  out8h = (_Float16*) alloc((size_t)B_ * 320 * 2);
  float*     pre   = (float*)    alloc((size_t)B_ * E_ * 4);   // shared h5pre/h6pre/h7pre
  float*     cpart = (float*)    alloc((size_t)RSBLK * E_ * 2 * 4);  // 1.23 MB
  float*     cstat = (float*)    alloc((size_t)E_ * 2 * 4);
  size_t part_bytes = (size_t)BKSPLIT * B_ * E_ * 4;           // 39.3 MB
  char* scratch = alloc(part_bytes);
  float* a     = (float*)scratch;                              // [R_][16] 6.55 MB (phase 1)
  float* sabs  = a + (size_t)R_ * 16;
  float* sstat = sabs + R_;
  float* part  = (float*)scratch;                              // reused after k_pool

  // prep: metadata + all weight conversions
  hipLaunchKernelGGL(k_meta, dim3((NPOS + 255) / 256), dim3(256), 0, stream, meta);
  hipLaunchKernelGGL(k_wg3, dim3(NPOS, 5), dim3(256), 0, stream, fc7w, v, meta, Wgf);
  hipLaunchKernelGGL(k_wf, dim3(19, 5), dim3(256), 0, stream, fc5w, Wf5, 300, 600, 19);
  hipLaunchKernelGGL(k_wf, dim3(10, 5), dim3(256), 0, stream, fc6w, Wf6, 300, 300, 19);
  hipLaunchKernelGGL(k_wf, dim3(19, 5), dim3(256), 0, stream, fc8w, Wf8, 300, 600, 19);
  hipLaunchKernelGGL(k_wf, dim3(10, 16), dim3(256), 0, stream, lemb, WfL, 1000, 300, 63);
  // attention pools
  hipLaunchKernelGGL(k_attn2, dim3(R_ / 128), dim3(256), 0, stream, x, fc1w, fc1b, fc3w, fc3b, a, sabs);
  hipLaunchKernelGGL(k_attnstats, dim3(S_, 2), dim3(256), 0, stream, a, sstat);
  hipLaunchKernelGGL(k_pool, dim3(B_), dim3(256), 0, stream, x, a, sabs, sstat, q1, q2, hh);
  // fc5 (f16 MFMA, ksplit 4) + BN -> h5h
  hipLaunchKernelGGL(k_gemmf, dim3(32, 2, 4), dim3(256), 0, stream, hh, 608, Wf5, 19, part, 300, 19, 5);
  hipLaunchKernelGGL(k_reduce_stat, dim3(RSBLK), dim3(256), 0, stream, part, pre, cpart, 4);
  hipLaunchKernelGGL(k_colstat_fin, dim3(E_), dim3(256), 0, stream, cpart, cstat, E_, RSBLK, B_);
  hipLaunchKernelGGL(k_norm_h5h, dim3((B_ * 320) / 256), dim3(256), 0, stream, pre, cstat, h5h);
  // fc6 + BN -> hcath[:, :300]
  hipLaunchKernelGGL(k_gemmf, dim3(32, 2, 4), dim3(256), 0, stream, h5h, 320, Wf6, 19, part, 300, 10, 3);
  hipLaunchKernelGGL(k_reduce_stat, dim3(RSBLK), dim3(256), 0, stream, part, pre, cpart, 4);
  hipLaunchKernelGGL(k_colstat_fin, dim3(E_), dim3(256), 0, stream, cpart, cstat, E_, RSBLK, B_);
  hipLaunchKernelGGL(k_norm_hcat, dim3((B_ * 300 + 255) / 256), dim3(256), 0, stream, pre, cstat, hcath, 0, 0);
  // cross-feature GEMM v5 + BN -> hcath[:, 300:] (+pad)
  hipLaunchKernelGGL(k_bigmm5, dim3(BKSPLIT * 32), dim3(256), 0, stream, Wgf, h5h, part);
  hipLaunchKernelGGL(k_reduce_stat, dim3(RSBLK), dim3(256), 0, stream, part, pre, cpart, BKSPLIT);
  hipLaunchKernelGGL(k_colstat_fin, dim3(E_), dim3(256), 0, stream, cpart, cstat, E_, RSBLK, B_);
  hipLaunchKernelGGL(k_norm_hcat, dim3((B_ * 308 + 255) / 256), dim3(256), 0, stream, pre, cstat, hcath, 300, 8);
  // fc8 (ksplit 4) + bias -> out8h f16
  hipLaunchKernelGGL(k_gemmf, dim3(32, 2, 4), dim3(256), 0, stream, hcath, 608, Wf8, 19, part, 300, 19, 5);
  hipLaunchKernelGGL(k_redbias_h, dim3((B_ * 320) / 256), dim3(256), 0, stream, part, fc8b, out8h, 4);
  // label projection (direct f32 out)
  hipLaunchKernelGGL(k_gemmf, dim3(32, 7, 1), dim3(256), 0, stream, out8h, 320, WfL, 63, out, 1000, 10, 10);
}

// Round 4
// 519.876 us; speedup vs baseline: 1.0440x; 1.0117x over previous
//
#include <hip/hip_runtime.h>

#define B_ 2048
#define S_ 50
#define E_ 300
#define NPAIR 44850
#define R_ (B_ * S_)            // 102400 rows for attn fc
#define PADSCORE (-4294967295.0f)
#define RSBLK 512               // blocks for k_reduce_stat (4 rows each)
#define RSROWS (B_ / RSBLK)

// ---- c-major padded chunk schedule for the cross-feature GEMM ----
// c-block c (cols [32c,32c+32)): i runs 0..Lc-1, Lc = min(299,32c+31) padded to x8.
// Lc = 32(c+1) for c<=8, 304 for c=9. cum(c) = 16*c*(c+1); NPOS = 1744.
#define NPOS 1744
#define BKSPLIT 16
#define BCPS 112                // pos per ks slice, multiple of 8; 16*112 >= 1744

typedef _Float16 h8 __attribute__((ext_vector_type(8)));
typedef float f4 __attribute__((ext_vector_type(4)));

// ---------- chunk metadata (c-major): meta[pos] = i | (j0<<16), j0 = 32c ----------
__global__ void k_meta(int* __restrict__ meta) {
  int pos = blockIdx.x * 256 + threadIdx.x;
  if (pos >= NPOS) return;
  int c = 0;
  #pragma unroll
  for (int cc = 1; cc < 10; cc++) if (pos >= 16 * cc * (cc + 1)) c = cc;
  meta[pos] = (pos - 16 * c * (c + 1)) | ((c * 32) << 16);
}

// ---------- Wgf in MFMA B-fragment order (cross-feature weights * g) ----------
// Padded chunks (i beyond real range) produce all-zero B via the j>i mask.
__global__ __launch_bounds__(256) void k_wg3(
    const float* __restrict__ w7, const float* __restrict__ v,
    const int* __restrict__ meta, _Float16* __restrict__ Wgf) {
  __shared__ float gL[32];
  const int ch = blockIdx.x;
  const int mt = meta[ch];
  const int i = mt & 0xffff, j0 = mt >> 16;
  const int t = threadIdx.x;
  if (t < 32) {
    int j = j0 + t;
    float g = 0.f;
    if (j > i && j < 300)
      g = v[i*4+0]*v[j*4+0] + v[i*4+1]*v[j*4+1] + v[i*4+2]*v[j*4+2] + v[i*4+3]*v[j*4+3];
    gL[t] = g;
  }
  __syncthreads();
  const int grp = blockIdx.y * 4 + (t >> 6);
  const int lane = t & 63, l16 = lane & 15, quad = lane >> 4;
  const int e = grp * 16 + l16;
  const int ibase = i * (599 - i) / 2 - i - 1;   // p = ibase + j
  h8 outv;
  #pragma unroll
  for (int tt = 0; tt < 8; tt++) {
    int k = quad * 8 + tt;
    int j = j0 + k;
    float val = 0.f;
    if (j > i && j < 300 && e < 300)
      val = w7[(size_t)e * NPAIR + ibase + j] * gL[k];
    outv[tt] = (_Float16)val;
  }
  *(h8*)&Wgf[(((size_t)ch * 20 + grp) * 64 + lane) * 8] = outv;
}

// ---------- generic weight -> MFMA B-fragment order converter ----------
__global__ __launch_bounds__(256) void k_wf(
    const float* __restrict__ w, _Float16* __restrict__ Wf,
    int N, int K, int ngrp) {
  const int kt = blockIdx.x;
  const int grp = blockIdx.y * 4 + (threadIdx.x >> 6);
  const int lane = threadIdx.x & 63, l16 = lane & 15, quad = lane >> 4;
  const int e = grp * 16 + l16;
  if (grp >= ngrp) return;
  h8 o;
  #pragma unroll
  for (int tt = 0; tt < 8; tt++) {
    int k = kt * 32 + quad * 8 + tt;
    float val = (e < N && k < K) ? w[(size_t)e * K + k] : 0.f;
    o[tt] = (_Float16)val;
  }
  *(h8*)&Wf[(((size_t)kt * ngrp + grp) * 64 + lane) * 8] = o;
}

// ---------- attn fc: a[r][16] = relu(x[r] @ w^T + b), sabs[r] = sum|x[r]| ----------
__global__ __launch_bounds__(256) void k_attn2(
    const float* __restrict__ x, const float* __restrict__ w1, const float* __restrict__ b1,
    const float* __restrict__ w3, const float* __restrict__ b3,
    float* __restrict__ a, float* __restrict__ sabs) {
  __shared__ float xs[128][68];
  __shared__ float wL[16][308];
  const int tid = threadIdx.x;
  const int r0 = blockIdx.x * 128;
  for (int u = tid; u < 16 * 75; u += 256) {
    int t = u / 75, q = u - t * 75;
    float4 v4 = (t < 8) ? *(const float4*)&w1[t * 300 + q * 4]
                        : *(const float4*)&w3[(t - 8) * 300 + q * 4];
    *(float4*)&wL[t][q * 4] = v4;
  }
  const int rg = tid >> 3, tg = tid & 7;
  float acc[4][2] = {};
  float sa[4] = {};
  for (int k0 = 0; k0 < 300; k0 += 64) {
    int w = min(64, 300 - k0);
    __syncthreads();
    #pragma unroll
    for (int it = 0; it < 8; it++) {
      int u = tid + it * 256;
      int r = u >> 4, q = u & 15;
      float4 v4 = {0.f, 0.f, 0.f, 0.f};
      if (q * 4 < w) v4 = *(const float4*)&x[(size_t)(r0 + r) * 300 + k0 + q * 4];
      *(float4*)&xs[r][q * 4] = v4;
    }
    __syncthreads();
    for (int q = 0; q < (w >> 2); q++) {
      float4 w0 = *(float4*)&wL[tg * 2][k0 + q * 4];
      float4 w1v = *(float4*)&wL[tg * 2 + 1][k0 + q * 4];
      #pragma unroll
      for (int k2 = 0; k2 < 4; k2++) {
        float4 xv = *(float4*)&xs[rg + 32 * k2][q * 4];
        acc[k2][0] += xv.x * w0.x + xv.y * w0.y + xv.z * w0.z + xv.w * w0.w;
        acc[k2][1] += xv.x * w1v.x + xv.y * w1v.y + xv.z * w1v.z + xv.w * w1v.w;
        if (tg == 0)
          sa[k2] += fabsf(xv.x) + fabsf(xv.y) + fabsf(xv.z) + fabsf(xv.w);
      }
    }
  }
  int t0 = tg * 2;
  float bb0 = (t0 < 8) ? b1[t0] : b3[t0 - 8];
  float bb1 = (t0 + 1 < 8) ? b1[t0 + 1] : b3[t0 + 1 - 8];
  #pragma unroll
  for (int k2 = 0; k2 < 4; k2++) {
    size_t r = r0 + rg + 32 * k2;
    a[r * 16 + t0]     = fmaxf(acc[k2][0] + bb0, 0.f);
    a[r * 16 + t0 + 1] = fmaxf(acc[k2][1] + bb1, 0.f);
    if (tg == 0) sabs[r] = sa[k2];
  }
}

// ---------- attn BN stats over (B,T) per s ----------
__global__ void k_attnstats(const float* __restrict__ a, float* __restrict__ sstat) {
  int s = blockIdx.x, pool = blockIdx.y;
  float sum = 0.f, sq = 0.f;
  for (int b = threadIdx.x; b < B_; b += blockDim.x) {
    const float* row = &a[((size_t)b * S_ + s) * 16 + pool * 8];
    #pragma unroll
    for (int t = 0; t < 8; t++) { float v = row[t]; sum += v; sq += v * v; }
  }
  __shared__ float rs[2][4];
  int wave = threadIdx.x >> 6, lane = threadIdx.x & 63;
  #pragma unroll
  for (int off = 32; off; off >>= 1) { sum += __shfl_xor(sum, off); sq += __shfl_xor(sq, off); }
  if (lane == 0) { rs[0][wave] = sum; rs[1][wave] = sq; }
  __syncthreads();
  if (threadIdx.x == 0) {
    float S = rs[0][0] + rs[0][1] + rs[0][2] + rs[0][3];
    float Q = rs[1][0] + rs[1][1] + rs[1][2] + rs[1][3];
    float n = (float)(B_ * 8);
    float m = S / n;
    float var = Q / n - m * m;
    sstat[(pool * S_ + s) * 2 + 0] = m;
    sstat[(pool * S_ + s) * 2 + 1] = rsqrtf(var + 1e-5f);
  }
}

// ---------- scores + softmax + weighted pool -> hh f16 [B][608] (zero-padded) ----------
__global__ __launch_bounds__(256) void k_pool(
    const float* __restrict__ x, const float* __restrict__ a,
    const float* __restrict__ sabs, const float* __restrict__ sstat,
    const float* __restrict__ q1, const float* __restrict__ q2,
    _Float16* __restrict__ hh) {
  int b = blockIdx.x;
  __shared__ float w1s[S_], w2s[S_];
  int tid = threadIdx.x;
  if (tid < S_) {
    float sc1 = 0.f, sc2 = 0.f;
    const float* r1 = &a[((size_t)b * S_ + tid) * 16];
    const float* r2 = r1 + 8;
    float m1 = sstat[(0 * S_ + tid) * 2], rr1 = sstat[(0 * S_ + tid) * 2 + 1];
    float m2 = sstat[(1 * S_ + tid) * 2], rr2 = sstat[(1 * S_ + tid) * 2 + 1];
    #pragma unroll
    for (int t = 0; t < 8; t++) {
      sc1 += (r1[t] - m1) * rr1 * q1[t];
      sc2 += (r2[t] - m2) * rr2 * q2[t];
    }
    if (sabs[(size_t)b * S_ + tid] == 0.f) { sc1 = PADSCORE; sc2 = PADSCORE; }
    w1s[tid] = sc1; w2s[tid] = sc2;
  }
  __syncthreads();
  if (tid < 64) {
    float v1 = (tid < S_) ? w1s[tid] : -3.0e38f;
    float v2 = (tid < S_) ? w2s[tid] : -3.0e38f;
    float m1 = v1, m2 = v2;
    #pragma unroll
    for (int off = 32; off; off >>= 1) {
      m1 = fmaxf(m1, __shfl_xor(m1, off));
      m2 = fmaxf(m2, __shfl_xor(m2, off));
    }
    float e1 = (tid < S_) ? expf(v1 - m1) : 0.f;
    float e2 = (tid < S_) ? expf(v2 - m2) : 0.f;
    float s1 = e1, s2 = e2;
    #pragma unroll
    for (int off = 32; off; off >>= 1) { s1 += __shfl_xor(s1, off); s2 += __shfl_xor(s2, off); }
    if (tid < S_) { w1s[tid] = e1 / s1; w2s[tid] = e2 / s2; }
  }
  __syncthreads();
  for (int e = tid; e < E_; e += 256) {
    float p1 = 0.f, p2 = 0.f;
    for (int s = 0; s < S_; s++) {
      float xv = x[((size_t)b * S_ + s) * E_ + e];
      p1 += xv * w1s[s];
      p2 += xv * w2s[s];
    }
    hh[(size_t)b * 608 + e]       = (_Float16)p1;
    hh[(size_t)b * 608 + 300 + e] = (_Float16)p2;
  }
  if (tid < 8) hh[(size_t)b * 608 + 600 + tid] = (_Float16)0.f;
}

// ---------- f16 MFMA GEMM (round-1 proven LDS version) ----------
__global__ __launch_bounds__(256) void k_gemmf(
    const _Float16* __restrict__ Xh, int ldx,
    const _Float16* __restrict__ Wf, int ngrp,
    float* __restrict__ dst, int N,
    int nchunk, int cps) {
  __shared__ _Float16 XL[64][328];
  const int mblk = blockIdx.x, nblk = blockIdx.y, ks = blockIdx.z;
  const int tid = threadIdx.x;
  const int wave = tid >> 6, lane = tid & 63, quad = lane >> 4, l16 = lane & 15;
  const int wm = wave >> 1, wn = wave & 1;
  const int ck0 = ks * cps, ck1 = min(nchunk, ck0 + cps);
  const int ncol8 = (ck1 - ck0) * 4;
  {
    const _Float16* src = Xh + (size_t)mblk * 64 * ldx + ck0 * 32;
    for (int u = tid; u < 64 * ncol8; u += 256) {
      int r = u / ncol8, c8 = u - r * ncol8;
      *(h8*)&XL[r][c8 * 8] = *(const h8*)&src[(size_t)r * ldx + c8 * 8];
    }
  }
  __syncthreads();

  f4 acc[2][5];
  #pragma unroll
  for (int i = 0; i < 2; i++)
    #pragma unroll
    for (int j = 0; j < 5; j++) acc[i][j] = (f4){0.f, 0.f, 0.f, 0.f};

  const int gbase = nblk * 10 + wn * 5;
  const _Float16* wb = Wf + ((size_t)gbase * 64 + lane) * 8;
  h8 bA[5], bB[5];
  #define LOADB(DST, CH)                                                        \
    _Pragma("unroll")                                                           \
    for (int nt = 0; nt < 5; nt++)                                              \
      DST[nt] = (gbase + nt < ngrp)                                             \
          ? *(const h8*)&wb[((size_t)(CH) * ngrp + nt) * 512]                   \
          : (h8){0, 0, 0, 0, 0, 0, 0, 0};

  if (ck0 < ck1) { LOADB(bA, ck0); }
  if (ck0 + 1 < ck1) { LOADB(bB, ck0 + 1); }

  auto step = [&](int ch, h8* bf) {
    int c0 = (ch - ck0) * 32 + quad * 8;
    h8 af[2];
    #pragma unroll
    for (int mi = 0; mi < 2; mi++)
      af[mi] = *(const h8*)&XL[wm * 32 + mi * 16 + l16][c0];
    #pragma unroll
    for (int mi = 0; mi < 2; mi++)
      #pragma unroll
      for (int nt = 0; nt < 5; nt++)
        acc[mi][nt] = __builtin_amdgcn_mfma_f32_16x16x32_f16(af[mi], bf[nt], acc[mi][nt], 0, 0, 0);
  };

  int ch = ck0;
  while (ch < ck1) {
    step(ch, bA);
    if (ch + 2 < ck1) { LOADB(bA, ch + 2); }
    ch++;
    if (ch < ck1) {
      step(ch, bB);
      if (ch + 2 < ck1) { LOADB(bB, ch + 2); }
      ch++;
    }
  }
  #undef LOADB

  float* d = dst + (size_t)ks * ((size_t)B_ * N);
  #pragma unroll
  for (int mi = 0; mi < 2; mi++) {
    int b = mblk * 64 + wm * 32 + mi * 16 + quad * 4;
    #pragma unroll
    for (int nt = 0; nt < 5; nt++) {
      int e = (gbase + nt) * 16 + l16;
      if (e < N) {
        #pragma unroll
        for (int r = 0; r < 4; r++)
          d[(size_t)(b + r) * N + e] = acc[mi][nt][r];
      }
    }
  }
}

// ---------- fused split-K reduce + column-stat partials (512 blocks x 4 rows) ----------
__global__ __launch_bounds__(256) void k_reduce_stat(
    const float* __restrict__ part, float* __restrict__ pre,
    float* __restrict__ cpart, int ksp) {
  int blk = blockIdx.x;              // RSBLK blocks x RSROWS rows
  int r0 = blk * RSROWS;
  for (int c = threadIdx.x; c < E_; c += 256) {
    float s = 0.f, q = 0.f;
    #pragma unroll
    for (int rr = 0; rr < RSROWS; rr++) {
      int r = r0 + rr;
      float v = 0.f;
      for (int k2 = 0; k2 < ksp; k2++)
        v += part[(size_t)k2 * (B_ * E_) + (size_t)r * E_ + c];
      pre[(size_t)r * E_ + c] = v;
      s += v; q += v * v;
    }
    cpart[((size_t)blk * E_ + c) * 2 + 0] = s;
    cpart[((size_t)blk * E_ + c) * 2 + 1] = q;
  }
}

// ---------- column-stat finalize (one block per column, tree reduce) ----------
__global__ __launch_bounds__(256) void k_colstat_fin(
    const float* __restrict__ part, float* __restrict__ stat,
    int N, int nparts, int M) {
  int c = blockIdx.x;
  if (c >= N) return;
  float s = 0.f, q = 0.f;
  for (int p = threadIdx.x; p < nparts; p += 256) {
    s += part[((size_t)p * N + c) * 2 + 0];
    q += part[((size_t)p * N + c) * 2 + 1];
  }
  #pragma unroll
  for (int off = 32; off; off >>= 1) { s += __shfl_xor(s, off); q += __shfl_xor(q, off); }
  __shared__ float rs[2][4];
  int wave = threadIdx.x >> 6, lane = threadIdx.x & 63;
  if (lane == 0) { rs[0][wave] = s; rs[1][wave] = q; }
  __syncthreads();
  if (threadIdx.x == 0) {
    float S = rs[0][0] + rs[0][1] + rs[0][2] + rs[0][3];
    float Q = rs[1][0] + rs[1][1] + rs[1][2] + rs[1][3];
    float m = S / (float)M;
    float var = Q / (float)M - m * m;
    stat[c * 2 + 0] = m;
    stat[c * 2 + 1] = rsqrtf(var + 1e-5f);
  }
}

// ---------- normalize -> h5h f16 [B][320] (zero-padded) ----------
__global__ void k_norm_h5h(const float* __restrict__ X, const float* __restrict__ stat,
                           _Float16* __restrict__ h5h) {
  int idx = blockIdx.x * 256 + threadIdx.x;
  if (idx >= B_ * 320) return;
  int b = idx / 320, c = idx - b * 320;
  if (c < E_) {
    float v = (X[(size_t)b * E_ + c] - stat[c * 2]) * stat[c * 2 + 1];
    h5h[idx] = (_Float16)v;
  } else {
    h5h[idx] = (_Float16)0.f;
  }
}

// ---------- normalize -> hcath f16 [B][608] at column offset (pad on off=300 pass) ----------
__global__ void k_norm_hcat(const float* __restrict__ X, const float* __restrict__ stat,
                            _Float16* __restrict__ Y, int off, int pad) {
  int W = 300 + pad;
  int idx = blockIdx.x * 256 + threadIdx.x;
  if (idx >= B_ * W) return;
  int b = idx / W, c = idx - b * W;
  if (c < 300) {
    float v = (X[(size_t)b * E_ + c] - stat[c * 2]) * stat[c * 2 + 1];
    Y[(size_t)b * 608 + off + c] = (_Float16)v;
  } else {
    Y[(size_t)b * 608 + 600 + (c - 300)] = (_Float16)0.f;
  }
}

// ---------- fc8 epilogue: reduce ksp partials + bias -> out8h f16 [B][320] ----------
__global__ void k_redbias_h(const float* __restrict__ part, const float* __restrict__ bias,
                            _Float16* __restrict__ out8h, int ksp) {
  int idx = blockIdx.x * 256 + threadIdx.x;
  if (idx >= B_ * 320) return;
  int b = idx / 320, c = idx - b * 320;
  if (c < E_) {
    float s = bias[c];
    for (int k2 = 0; k2 < ksp; k2++)
      s += part[(size_t)k2 * (B_ * E_) + (size_t)b * E_ + c];
    out8h[idx] = (_Float16)s;
  } else {
    out8h[idx] = (_Float16)0.f;
  }
}

// ---------- big MFMA GEMM v6: c-major, register A-side, deep pipeline ----------
// v5 + (a) hi8/vj double-buffer: next group's h5 scalars prefetched one group
// (~160 MFMA) ahead, removing the per-group serial L2 stall; (b) 4-deep B
// prefetch (4 rotating buffers, distance 4 positions). 2 waves/SIMD is the
// VGPR-capped occupancy, so all latency hiding is in-wave ILP.
__global__ __launch_bounds__(256, 2) void k_bigmm6(
    const _Float16* __restrict__ Wgf, const _Float16* __restrict__ h5h,
    float* __restrict__ part) {
  const int n = blockIdx.x;
  const int g = n & 31, mblk = n >> 5;
  const int ks = g >> 1, nblk = g & 1;
  const int tid = threadIdx.x;
  const int wave = tid >> 6, lane = tid & 63, quad = lane >> 4, l16 = lane & 15;
  const int wm = wave >> 1, wn = wave & 1;
  const int pos0 = ks * BCPS;
  const int pos1 = min(NPOS, pos0 + BCPS);

  const int gbase = nblk * 10 + wn * 5;
  const _Float16* wb = Wgf + ((size_t)gbase * 64 + lane) * 8;

  const _Float16* rowp[4];
  #pragma unroll
  for (int mi = 0; mi < 4; mi++)
    rowp[mi] = h5h + (size_t)(mblk * 128 + wm * 64 + mi * 16 + l16) * 320;

  f4 acc[4][5];
  #pragma unroll
  for (int i = 0; i < 4; i++)
    #pragma unroll
    for (int j = 0; j < 5; j++) acc[i][j] = (f4){0.f, 0.f, 0.f, 0.f};

  h8 bb[4][5], vjC[4], vjN[4], hi8C[4], hi8N[4];

  #define LOADB6(DST, POS)                                                     \
    _Pragma("unroll")                                                          \
    for (int nt = 0; nt < 5; nt++)                                             \
      DST[nt] = *(const h8*)&wb[(size_t)(POS) * 10240 + nt * 512];

  // initial c-block state for pos0 (cum(c) = 16*c*(c+1))
  int c = 0, cend = 32;
  while (pos0 >= cend) { c++; cend = (c < 9) ? 16 * (c + 1) * (c + 2) : NPOS; }
  int cumc = 16 * c * (c + 1);
  #pragma unroll
  for (int mi = 0; mi < 4; mi++) {
    vjC[mi]  = *(const h8*)&rowp[mi][c * 32 + quad * 8];
    hi8C[mi] = *(const h8*)&rowp[mi][pos0 - cumc];
  }
  #pragma unroll
  for (int q = 0; q < 4; q++) { LOADB6(bb[q], pos0 + q); }

  for (int p = pos0; p < pos1; p += 8) {
    const int pn = p + 8;
    // prefetch next group's A-side state (consumed one group later)
    int cN = c, cendN = cend, cumcN = cumc;
    bool adv = false;
    if (pn < pos1) {
      while (pn >= cendN) {
        cN++; cendN = (cN < 9) ? 16 * (cN + 1) * (cN + 2) : NPOS; adv = true;
      }
      if (adv) cumcN = 16 * cN * (cN + 1);
      #pragma unroll
      for (int mi = 0; mi < 4; mi++)
        hi8N[mi] = *(const h8*)&rowp[mi][pn - cumcN];
      if (adv) {
        #pragma unroll
        for (int mi = 0; mi < 4; mi++)
          vjN[mi] = *(const h8*)&rowp[mi][cN * 32 + quad * 8];
      }
    }
    // 8 positions, 4-buffer rotation, B prefetch distance 4
    #pragma unroll
    for (int t = 0; t < 8; t++) {
      #pragma unroll
      for (int mi = 0; mi < 4; mi++) {
        _Float16 hsc = hi8C[mi][t];
        h8 hs = {hsc, hsc, hsc, hsc, hsc, hsc, hsc, hsc};
        h8 af = vjC[mi] * hs;
        #pragma unroll
        for (int nt = 0; nt < 5; nt++)
          acc[mi][nt] = __builtin_amdgcn_mfma_f32_16x16x32_f16(af, bb[t & 3][nt], acc[mi][nt], 0, 0, 0);
      }
      LOADB6(bb[t & 3], p + t + 4);
    }
    // rotate A-side state
    if (pn < pos1) {
      #pragma unroll
      for (int mi = 0; mi < 4; mi++) hi8C[mi] = hi8N[mi];
      if (adv) {
        #pragma unroll
        for (int mi = 0; mi < 4; mi++) vjC[mi] = vjN[mi];
        c = cN; cend = cendN; cumc = cumcN;
      }
    }
  }
  #undef LOADB6

  float* dst = part + (size_t)ks * (B_ * E_);
  const int b0 = mblk * 128 + wm * 64;
  #pragma unroll
  for (int mi = 0; mi < 4; mi++) {
    int b = b0 + mi * 16 + quad * 4;
    #pragma unroll
    for (int nt = 0; nt < 5; nt++) {
      int e = (gbase + nt) * 16 + l16;
      if (e < E_) {
        #pragma unroll
        for (int r = 0; r < 4; r++)
          dst[(size_t)(b + r) * E_ + e] = acc[mi][nt][r];
      }
    }
  }
}

extern "C" void kernel_launch(void* const* d_in, const int* in_sizes, int n_in,
                              void* d_out, int out_size, void* d_ws, size_t ws_size,
                              hipStream_t stream) {
  const float* x    = (const float*)d_in[0];
  const float* lemb = (const float*)d_in[1];
  const float* fc1w = (const float*)d_in[2];
  const float* fc1b = (const float*)d_in[3];
  const float* q1   = (const float*)d_in[4];
  const float* fc3w = (const float*)d_in[5];
  const float* fc3b = (const float*)d_in[6];
  const float* q2   = (const float*)d_in[7];
  const float* fc5w = (const float*)d_in[8];
  const float* fc6w = (const float*)d_in[10];
  const float* fc7w = (const float*)d_in[12];
  const float* fc8w = (const float*)d_in[14];
  const float* fc8b = (const float*)d_in[15];
  const float* v    = (const float*)d_in[16];
  float* out = (float*)d_out;
  (void)in_sizes; (void)n_in; (void)out_size; (void)ws_size;

  char* base = (char*)d_ws;
  size_t off = 0;
  auto alloc = [&](size_t nbytes) -> char* {
    char* p = base + off;
    off = (off + nbytes + 255) & ~(size_t)255;
    return p;
  };
  int*       meta  = (int*)      alloc((size_t)NPOS * 4);
  _Float16*  Wgf   = (_Float16*) alloc((size_t)(NPOS + 8) * 20 * 64 * 8 * 2);  // 35.9 MB (+slack for prefetch overrun)
  _Float16*  Wf5   = (_Float16*) alloc((size_t)19 * 19 * 512 * 2);
  _Float16*  Wf6   = (_Float16*) alloc((size_t)10 * 19 * 512 * 2);
  _Float16*  Wf8   = (_Float16*) alloc((size_t)19 * 19 * 512 * 2);
  _Float16*  WfL   = (_Float16*) alloc((size_t)10 * 63 * 512 * 2);
  _Float16*  hh    = (_Float16*) alloc((size_t)B_ * 608 * 2);
  _Float16*  h5h   = (_Float16*) alloc((size_t)B_ * 320 * 2);
  _Float16*  hcath = (_Float16*) alloc((size_t)B_ * 608 * 2);
  _Float16*  out8h = (_Float16*) alloc((size_t)B_ * 320 * 2);
  float*     pre   = (float*)    alloc((size_t)B_ * E_ * 4);   // shared h5pre/h6pre/h7pre
  float*     cpart = (float*)    alloc((size_t)RSBLK * E_ * 2 * 4);  // 1.23 MB
  float*     cstat = (float*)    alloc((size_t)E_ * 2 * 4);
  size_t part_bytes = (size_t)BKSPLIT * B_ * E_ * 4;           // 39.3 MB
  char* scratch = alloc(part_bytes);
  float* a     = (float*)scratch;                              // [R_][16] 6.55 MB (phase 1)
  float* sabs  = a + (size_t)R_ * 16;
  float* sstat = sabs + R_;
  float* part  = (float*)scratch;                              // reused after k_pool

  // prep: metadata + all weight conversions
  hipLaunchKernelGGL(k_meta, dim3((NPOS + 255) / 256), dim3(256), 0, stream, meta);
  hipLaunchKernelGGL(k_wg3, dim3(NPOS, 5), dim3(256), 0, stream, fc7w, v, meta, Wgf);
  hipLaunchKernelGGL(k_wf, dim3(19, 5), dim3(256), 0, stream, fc5w, Wf5, 300, 600, 19);
  hipLaunchKernelGGL(k_wf, dim3(10, 5), dim3(256), 0, stream, fc6w, Wf6, 300, 300, 19);
  hipLaunchKernelGGL(k_wf, dim3(19, 5), dim3(256), 0, stream, fc8w, Wf8, 300, 600, 19);
  hipLaunchKernelGGL(k_wf, dim3(10, 16), dim3(256), 0, stream, lemb, WfL, 1000, 300, 63);
  // attention pools
  hipLaunchKernelGGL(k_attn2, dim3(R_ / 128), dim3(256), 0, stream, x, fc1w, fc1b, fc3w, fc3b, a, sabs);
  hipLaunchKernelGGL(k_attnstats, dim3(S_, 2), dim3(256), 0, stream, a, sstat);
  hipLaunchKernelGGL(k_pool, dim3(B_), dim3(256), 0, stream, x, a, sabs, sstat, q1, q2, hh);
  // fc5 (f16 MFMA, ksplit 4) + BN -> h5h
  hipLaunchKernelGGL(k_gemmf, dim3(32, 2, 4), dim3(256), 0, stream, hh, 608, Wf5, 19, part, 300, 19, 5);
  hipLaunchKernelGGL(k_reduce_stat, dim3(RSBLK), dim3(256), 0, stream, part, pre, cpart, 4);
  hipLaunchKernelGGL(k_colstat_fin, dim3(E_), dim3(256), 0, stream, cpart, cstat, E_, RSBLK, B_);
  hipLaunchKernelGGL(k_norm_h5h, dim3((B_ * 320) / 256), dim3(256), 0, stream, pre, cstat, h5h);
  // fc6 + BN -> hcath[:, :300]
  hipLaunchKernelGGL(k_gemmf, dim3(32, 2, 4), dim3(256), 0, stream, h5h, 320, Wf6, 19, part, 300, 10, 3);
  hipLaunchKernelGGL(k_reduce_stat, dim3(RSBLK), dim3(256), 0, stream, part, pre, cpart, 4);
  hipLaunchKernelGGL(k_colstat_fin, dim3(E_), dim3(256), 0, stream, cpart, cstat, E_, RSBLK, B_);
  hipLaunchKernelGGL(k_norm_hcat, dim3((B_ * 300 + 255) / 256), dim3(256), 0, stream, pre, cstat, hcath, 0, 0);
  // cross-feature GEMM v6 + BN -> hcath[:, 300:] (+pad)
  hipLaunchKernelGGL(k_bigmm6, dim3(BKSPLIT * 32), dim3(256), 0, stream, Wgf, h5h, part);
  hipLaunchKernelGGL(k_reduce_stat, dim3(RSBLK), dim3(256), 0, stream, part, pre, cpart, BKSPLIT);
  hipLaunchKernelGGL(k_colstat_fin, dim3(E_), dim3(256), 0, stream, cpart, cstat, E_, RSBLK, B_);
  hipLaunchKernelGGL(k_norm_hcat, dim3((B_ * 308 + 255) / 256), dim3(256), 0, stream, pre, cstat, hcath, 300, 8);
  // fc8 (ksplit 4) + bias -> out8h f16
  hipLaunchKernelGGL(k_gemmf, dim3(32, 2, 4), dim3(256), 0, stream, hcath, 608, Wf8, 19, part, 300, 19, 5);
  hipLaunchKernelGGL(k_redbias_h, dim3((B_ * 320) / 256), dim3(256), 0, stream, part, fc8b, out8h, 4);
  // label projection (direct f32 out)
  hipLaunchKernelGGL(k_gemmf, dim3(32, 7, 1), dim3(256), 0, stream, out8h, 320, WfL, 63, out, 1000, 10, 10);
}

// Round 6
// 509.900 us; speedup vs baseline: 1.0644x; 1.0196x over previous
//
#include <hip/hip_runtime.h>

#define B_ 2048
#define S_ 50
#define E_ 300
#define NPAIR 44850
#define R_ (B_ * S_)            // 102400 rows for attn fc
#define PADSCORE (-4294967295.0f)
#define RSBLK 512               // blocks for k_reduce_stat (4 rows each)
#define RSROWS (B_ / RSBLK)

// ---- c-major padded chunk schedule for the cross-feature GEMM ----
// c-block c (cols [32c,32c+32)): i runs 0..Lc-1 padded to x8; cum(c)=16c(c+1); NPOS=1744.
#define NPOS 1744
#define BKSPLIT 16
#define BCPS 112                // pos per ks slice

typedef _Float16 h8 __attribute__((ext_vector_type(8)));
typedef float f4 __attribute__((ext_vector_type(4)));

// ---------- generic weight -> MFMA B-fragment order (device body) ----------
__device__ __forceinline__ void wf_body(
    const float* __restrict__ w, _Float16* __restrict__ Wf,
    int N, int K, int ngrp, int kt, int yblk, int t) {
  const int grp = yblk * 4 + (t >> 6);
  const int lane = t & 63, l16 = lane & 15, quad = lane >> 4;
  const int e = grp * 16 + l16;
  if (grp >= ngrp) return;
  h8 o;
  #pragma unroll
  for (int tt = 0; tt < 8; tt++) {
    int k = kt * 32 + quad * 8 + tt;
    float val = (e < N && k < K) ? w[(size_t)e * K + k] : 0.f;
    o[tt] = (_Float16)val;
  }
  *(h8*)&Wf[(((size_t)kt * ngrp + grp) * 64 + lane) * 8] = o;
}

// ---------- fused prep: Wgf (c-major, g-scaled) + all 4 weight conversions ----------
__global__ __launch_bounds__(256) void k_prep(
    const float* __restrict__ w7, const float* __restrict__ v,
    _Float16* __restrict__ Wgf,
    const float* __restrict__ fc5w, _Float16* __restrict__ Wf5,
    const float* __restrict__ fc6w, _Float16* __restrict__ Wf6,
    const float* __restrict__ fc8w, _Float16* __restrict__ Wf8,
    const float* __restrict__ lemb, _Float16* __restrict__ WfL) {
  const int t = threadIdx.x;
  int bid = blockIdx.x;
  if (bid < NPOS * 5) {
    __shared__ float gL[32];
    const int pos = bid / 5, yblk = bid - pos * 5;
    int c = 0;
    #pragma unroll
    for (int cc = 1; cc < 10; cc++) if (pos >= 16 * cc * (cc + 1)) c = cc;
    const int i = pos - 16 * c * (c + 1), j0 = c * 32;
    if (t < 32) {
      int j = j0 + t;
      float g = 0.f;
      if (j > i && j < 300)
        g = v[i*4+0]*v[j*4+0] + v[i*4+1]*v[j*4+1] + v[i*4+2]*v[j*4+2] + v[i*4+3]*v[j*4+3];
      gL[t] = g;
    }
    __syncthreads();
    const int grp = yblk * 4 + (t >> 6);
    const int lane = t & 63, l16 = lane & 15, quad = lane >> 4;
    const int e = grp * 16 + l16;
    const int ibase = i * (599 - i) / 2 - i - 1;   // p = ibase + j
    h8 outv;
    #pragma unroll
    for (int tt = 0; tt < 8; tt++) {
      int k = quad * 8 + tt;
      int j = j0 + k;
      float val = 0.f;
      if (j > i && j < 300 && e < 300)
        val = w7[(size_t)e * NPAIR + ibase + j] * gL[k];
      outv[tt] = (_Float16)val;
    }
    *(h8*)&Wgf[(((size_t)pos * 20 + grp) * 64 + lane) * 8] = outv;
    return;
  }
  bid -= NPOS * 5;
  if (bid < 95) { wf_body(fc5w, Wf5, 300, 600, 19, bid / 5, bid % 5, t); return; }
  bid -= 95;
  if (bid < 50) { wf_body(fc6w, Wf6, 300, 300, 19, bid / 5, bid % 5, t); return; }
  bid -= 50;
  if (bid < 95) { wf_body(fc8w, Wf8, 300, 600, 19, bid / 5, bid % 5, t); return; }
  bid -= 95;
  wf_body(lemb, WfL, 1000, 300, 63, bid / 16, bid % 16, t);
}

// ---------- attn fc: a[r][16] = relu(x[r] @ w^T + b), sabs[r] = sum|x[r]| ----------
__global__ __launch_bounds__(256) void k_attn2(
    const float* __restrict__ x, const float* __restrict__ w1, const float* __restrict__ b1,
    const float* __restrict__ w3, const float* __restrict__ b3,
    float* __restrict__ a, float* __restrict__ sabs) {
  __shared__ float xs[128][68];
  __shared__ float wL[16][308];
  const int tid = threadIdx.x;
  const int r0 = blockIdx.x * 128;
  for (int u = tid; u < 16 * 75; u += 256) {
    int t = u / 75, q = u - t * 75;
    float4 v4 = (t < 8) ? *(const float4*)&w1[t * 300 + q * 4]
                        : *(const float4*)&w3[(t - 8) * 300 + q * 4];
    *(float4*)&wL[t][q * 4] = v4;
  }
  const int rg = tid >> 3, tg = tid & 7;
  float acc[4][2] = {};
  float sa[4] = {};
  for (int k0 = 0; k0 < 300; k0 += 64) {
    int w = min(64, 300 - k0);
    __syncthreads();
    #pragma unroll
    for (int it = 0; it < 8; it++) {
      int u = tid + it * 256;
      int r = u >> 4, q = u & 15;
      float4 v4 = {0.f, 0.f, 0.f, 0.f};
      if (q * 4 < w) v4 = *(const float4*)&x[(size_t)(r0 + r) * 300 + k0 + q * 4];
      *(float4*)&xs[r][q * 4] = v4;
    }
    __syncthreads();
    for (int q = 0; q < (w >> 2); q++) {
      float4 w0 = *(float4*)&wL[tg * 2][k0 + q * 4];
      float4 w1v = *(float4*)&wL[tg * 2 + 1][k0 + q * 4];
      #pragma unroll
      for (int k2 = 0; k2 < 4; k2++) {
        float4 xv = *(float4*)&xs[rg + 32 * k2][q * 4];
        acc[k2][0] += xv.x * w0.x + xv.y * w0.y + xv.z * w0.z + xv.w * w0.w;
        acc[k2][1] += xv.x * w1v.x + xv.y * w1v.y + xv.z * w1v.z + xv.w * w1v.w;
        if (tg == 0)
          sa[k2] += fabsf(xv.x) + fabsf(xv.y) + fabsf(xv.z) + fabsf(xv.w);
      }
    }
  }
  int t0 = tg * 2;
  float bb0 = (t0 < 8) ? b1[t0] : b3[t0 - 8];
  float bb1 = (t0 + 1 < 8) ? b1[t0 + 1] : b3[t0 + 1 - 8];
  #pragma unroll
  for (int k2 = 0; k2 < 4; k2++) {
    size_t r = r0 + rg + 32 * k2;
    a[r * 16 + t0]     = fmaxf(acc[k2][0] + bb0, 0.f);
    a[r * 16 + t0 + 1] = fmaxf(acc[k2][1] + bb1, 0.f);
    if (tg == 0) sabs[r] = sa[k2];
  }
}

// ---------- attn BN partial stats: grid (S,2,4), each block 512 b-rows ----------
__global__ void k_attnstats(const float* __restrict__ a, float* __restrict__ spart) {
  int s = blockIdx.x, pool = blockIdx.y, z = blockIdx.z;
  float sum = 0.f, sq = 0.f;
  for (int b = z * 512 + threadIdx.x; b < (z + 1) * 512; b += blockDim.x) {
    const float* row = &a[((size_t)b * S_ + s) * 16 + pool * 8];
    #pragma unroll
    for (int t = 0; t < 8; t++) { float v = row[t]; sum += v; sq += v * v; }
  }
  __shared__ float rs[2][4];
  int wave = threadIdx.x >> 6, lane = threadIdx.x & 63;
  #pragma unroll
  for (int off = 32; off; off >>= 1) { sum += __shfl_xor(sum, off); sq += __shfl_xor(sq, off); }
  if (lane == 0) { rs[0][wave] = sum; rs[1][wave] = sq; }
  __syncthreads();
  if (threadIdx.x == 0) {
    float S = rs[0][0] + rs[0][1] + rs[0][2] + rs[0][3];
    float Q = rs[1][0] + rs[1][1] + rs[1][2] + rs[1][3];
    spart[((size_t)(pool * S_ + s) * 4 + z) * 2 + 0] = S;
    spart[((size_t)(pool * S_ + s) * 4 + z) * 2 + 1] = Q;
  }
}

// ---------- scores + softmax + weighted pool -> hh f16 [B][608] (zero-padded) ----------
__global__ __launch_bounds__(256) void k_pool(
    const float* __restrict__ x, const float* __restrict__ a,
    const float* __restrict__ sabs, const float* __restrict__ spart,
    const float* __restrict__ q1, const float* __restrict__ q2,
    _Float16* __restrict__ hh) {
  int b = blockIdx.x;
  __shared__ float w1s[S_], w2s[S_];
  int tid = threadIdx.x;
  if (tid < S_) {
    float s1p = 0.f, q1p = 0.f, s2p = 0.f, q2p = 0.f;
    #pragma unroll
    for (int z = 0; z < 4; z++) {
      s1p += spart[((size_t)(0 * S_ + tid) * 4 + z) * 2 + 0];
      q1p += spart[((size_t)(0 * S_ + tid) * 4 + z) * 2 + 1];
      s2p += spart[((size_t)(1 * S_ + tid) * 4 + z) * 2 + 0];
      q2p += spart[((size_t)(1 * S_ + tid) * 4 + z) * 2 + 1];
    }
    const float nn = (float)(B_ * 8);
    float m1 = s1p / nn, rr1 = rsqrtf(q1p / nn - m1 * m1 + 1e-5f);
    float m2 = s2p / nn, rr2 = rsqrtf(q2p / nn - m2 * m2 + 1e-5f);
    float sc1 = 0.f, sc2 = 0.f;
    const float* r1 = &a[((size_t)b * S_ + tid) * 16];
    const float* r2 = r1 + 8;
    #pragma unroll
    for (int t = 0; t < 8; t++) {
      sc1 += (r1[t] - m1) * rr1 * q1[t];
      sc2 += (r2[t] - m2) * rr2 * q2[t];
    }
    if (sabs[(size_t)b * S_ + tid] == 0.f) { sc1 = PADSCORE; sc2 = PADSCORE; }
    w1s[tid] = sc1; w2s[tid] = sc2;
  }
  __syncthreads();
  if (tid < 64) {
    float v1 = (tid < S_) ? w1s[tid] : -3.0e38f;
    float v2 = (tid < S_) ? w2s[tid] : -3.0e38f;
    float m1 = v1, m2 = v2;
    #pragma unroll
    for (int off = 32; off; off >>= 1) {
      m1 = fmaxf(m1, __shfl_xor(m1, off));
      m2 = fmaxf(m2, __shfl_xor(m2, off));
    }
    float e1 = (tid < S_) ? expf(v1 - m1) : 0.f;
    float e2 = (tid < S_) ? expf(v2 - m2) : 0.f;
    float s1 = e1, s2 = e2;
    #pragma unroll
    for (int off = 32; off; off >>= 1) { s1 += __shfl_xor(s1, off); s2 += __shfl_xor(s2, off); }
    if (tid < S_) { w1s[tid] = e1 / s1; w2s[tid] = e2 / s2; }
  }
  __syncthreads();
  for (int e = tid; e < E_; e += 256) {
    float p1 = 0.f, p2 = 0.f;
    for (int s = 0; s < S_; s++) {
      float xv = x[((size_t)b * S_ + s) * E_ + e];
      p1 += xv * w1s[s];
      p2 += xv * w2s[s];
    }
    hh[(size_t)b * 608 + e]       = (_Float16)p1;
    hh[(size_t)b * 608 + 300 + e] = (_Float16)p2;
  }
  if (tid < 8) hh[(size_t)b * 608 + 600 + tid] = (_Float16)0.f;
}

// ---------- f16 MFMA GEMM (round-1 proven LDS version) ----------
__global__ __launch_bounds__(256) void k_gemmf(
    const _Float16* __restrict__ Xh, int ldx,
    const _Float16* __restrict__ Wf, int ngrp,
    float* __restrict__ dst, int N,
    int nchunk, int cps) {
  __shared__ _Float16 XL[64][328];
  const int mblk = blockIdx.x, nblk = blockIdx.y, ks = blockIdx.z;
  const int tid = threadIdx.x;
  const int wave = tid >> 6, lane = tid & 63, quad = lane >> 4, l16 = lane & 15;
  const int wm = wave >> 1, wn = wave & 1;
  const int ck0 = ks * cps, ck1 = min(nchunk, ck0 + cps);
  const int ncol8 = (ck1 - ck0) * 4;
  {
    const _Float16* src = Xh + (size_t)mblk * 64 * ldx + ck0 * 32;
    for (int u = tid; u < 64 * ncol8; u += 256) {
      int r = u / ncol8, c8 = u - r * ncol8;
      *(h8*)&XL[r][c8 * 8] = *(const h8*)&src[(size_t)r * ldx + c8 * 8];
    }
  }
  __syncthreads();

  f4 acc[2][5];
  #pragma unroll
  for (int i = 0; i < 2; i++)
    #pragma unroll
    for (int j = 0; j < 5; j++) acc[i][j] = (f4){0.f, 0.f, 0.f, 0.f};

  const int gbase = nblk * 10 + wn * 5;
  const _Float16* wb = Wf + ((size_t)gbase * 64 + lane) * 8;
  h8 bA[5], bB[5];
  #define LOADB(DST, CH)                                                        \
    _Pragma("unroll")                                                           \
    for (int nt = 0; nt < 5; nt++)                                              \
      DST[nt] = (gbase + nt < ngrp)                                             \
          ? *(const h8*)&wb[((size_t)(CH) * ngrp + nt) * 512]                   \
          : (h8){0, 0, 0, 0, 0, 0, 0, 0};

  if (ck0 < ck1) { LOADB(bA, ck0); }
  if (ck0 + 1 < ck1) { LOADB(bB, ck0 + 1); }

  auto step = [&](int ch, h8* bf) {
    int c0 = (ch - ck0) * 32 + quad * 8;
    h8 af[2];
    #pragma unroll
    for (int mi = 0; mi < 2; mi++)
      af[mi] = *(const h8*)&XL[wm * 32 + mi * 16 + l16][c0];
    #pragma unroll
    for (int mi = 0; mi < 2; mi++)
      #pragma unroll
      for (int nt = 0; nt < 5; nt++)
        acc[mi][nt] = __builtin_amdgcn_mfma_f32_16x16x32_f16(af[mi], bf[nt], acc[mi][nt], 0, 0, 0);
  };

  int ch = ck0;
  while (ch < ck1) {
    step(ch, bA);
    if (ch + 2 < ck1) { LOADB(bA, ch + 2); }
    ch++;
    if (ch < ck1) {
      step(ch, bB);
      if (ch + 2 < ck1) { LOADB(bB, ch + 2); }
      ch++;
    }
  }
  #undef LOADB

  float* d = dst + (size_t)ks * ((size_t)B_ * N);
  #pragma unroll
  for (int mi = 0; mi < 2; mi++) {
    int b = mblk * 64 + wm * 32 + mi * 16 + quad * 4;
    #pragma unroll
    for (int nt = 0; nt < 5; nt++) {
      int e = (gbase + nt) * 16 + l16;
      if (e < N) {
        #pragma unroll
        for (int r = 0; r < 4; r++)
          d[(size_t)(b + r) * N + e] = acc[mi][nt][r];
      }
    }
  }
}

// ---------- fused split-K reduce + column-stat partials (512 blocks x 4 rows) ----------
__global__ __launch_bounds__(256) void k_reduce_stat(
    const float* __restrict__ part, float* __restrict__ pre,
    float* __restrict__ cpart, int ksp) {
  int blk = blockIdx.x;              // RSBLK blocks x RSROWS rows
  int r0 = blk * RSROWS;
  for (int c = threadIdx.x; c < E_; c += 256) {
    float s = 0.f, q = 0.f;
    #pragma unroll
    for (int rr = 0; rr < RSROWS; rr++) {
      int r = r0 + rr;
      float v = 0.f;
      for (int k2 = 0; k2 < ksp; k2++)
        v += part[(size_t)k2 * (B_ * E_) + (size_t)r * E_ + c];
      pre[(size_t)r * E_ + c] = v;
      s += v; q += v * v;
    }
    cpart[((size_t)blk * E_ + c) * 2 + 0] = s;
    cpart[((size_t)blk * E_ + c) * 2 + 1] = q;
  }
}

// ---------- column-stat finalize (one block per column, tree reduce) ----------
__global__ __launch_bounds__(256) void k_colstat_fin(
    const float* __restrict__ part, float* __restrict__ stat,
    int N, int nparts, int M) {
  int c = blockIdx.x;
  if (c >= N) return;
  float s = 0.f, q = 0.f;
  for (int p = threadIdx.x; p < nparts; p += 256) {
    s += part[((size_t)p * N + c) * 2 + 0];
    q += part[((size_t)p * N + c) * 2 + 1];
  }
  #pragma unroll
  for (int off = 32; off; off >>= 1) { s += __shfl_xor(s, off); q += __shfl_xor(q, off); }
  __shared__ float rs[2][4];
  int wave = threadIdx.x >> 6, lane = threadIdx.x & 63;
  if (lane == 0) { rs[0][wave] = s; rs[1][wave] = q; }
  __syncthreads();
  if (threadIdx.x == 0) {
    float S = rs[0][0] + rs[0][1] + rs[0][2] + rs[0][3];
    float Q = rs[1][0] + rs[1][1] + rs[1][2] + rs[1][3];
    float m = S / (float)M;
    float var = Q / (float)M - m * m;
    stat[c * 2 + 0] = m;
    stat[c * 2 + 1] = rsqrtf(var + 1e-5f);
  }
}

// ---------- normalize -> h5h f16 [B][320] (zero-padded) ----------
__global__ void k_norm_h5h(const float* __restrict__ X, const float* __restrict__ stat,
                           _Float16* __restrict__ h5h) {
  int idx = blockIdx.x * 256 + threadIdx.x;
  if (idx >= B_ * 320) return;
  int b = idx / 320, c = idx - b * 320;
  if (c < E_) {
    float v = (X[(size_t)b * E_ + c] - stat[c * 2]) * stat[c * 2 + 1];
    h5h[idx] = (_Float16)v;
  } else {
    h5h[idx] = (_Float16)0.f;
  }
}

// ---------- normalize -> hcath f16 [B][608] at column offset (pad on off=300 pass) ----------
__global__ void k_norm_hcat(const float* __restrict__ X, const float* __restrict__ stat,
                            _Float16* __restrict__ Y, int off, int pad) {
  int W = 300 + pad;
  int idx = blockIdx.x * 256 + threadIdx.x;
  if (idx >= B_ * W) return;
  int b = idx / W, c = idx - b * W;
  if (c < 300) {
    float v = (X[(size_t)b * E_ + c] - stat[c * 2]) * stat[c * 2 + 1];
    Y[(size_t)b * 608 + off + c] = (_Float16)v;
  } else {
    Y[(size_t)b * 608 + 600 + (c - 300)] = (_Float16)0.f;
  }
}

// ---------- fc8 epilogue: reduce ksp partials + bias -> out8h f16 [B][320] ----------
__global__ void k_redbias_h(const float* __restrict__ part, const float* __restrict__ bias,
                            _Float16* __restrict__ out8h, int ksp) {
  int idx = blockIdx.x * 256 + threadIdx.x;
  if (idx >= B_ * 320) return;
  int b = idx / 320, c = idx - b * 320;
  if (c < E_) {
    float s = bias[c];
    for (int k2 = 0; k2 < ksp; k2++)
      s += part[(size_t)k2 * (B_ * E_) + (size_t)b * E_ + c];
    out8h[idx] = (_Float16)s;
  } else {
    out8h[idx] = (_Float16)0.f;
  }
}

// ---------- big MFMA GEMM v7: dedup-B wave layout, c-major, deep pipeline ----------
// Each wave owns a DISTINCT 80-col group slice (gbase = wave*5) -> every B
// fragment loaded exactly once per block (v6 loaded each twice via wm).
// M-tile 64 shared by all 4 waves (A-side reads are tiny/L1-hot).
// Grid 512 = 16 ks x 32 mblk; id%8 = ks%8 pins one ks B-slice per XCD L2.
__global__ __launch_bounds__(256, 2) void k_bigmm7(
    const _Float16* __restrict__ Wgf, const _Float16* __restrict__ h5h,
    float* __restrict__ part) {
  const int n = blockIdx.x;
  const int ks = n & 15, mblk = n >> 4;
  const int tid = threadIdx.x;
  const int wave = tid >> 6, lane = tid & 63, quad = lane >> 4, l16 = lane & 15;
  const int pos0 = ks * BCPS;
  const int pos1 = min(NPOS, pos0 + BCPS);

  const int gbase = wave * 5;
  const _Float16* wb = Wgf + ((size_t)gbase * 64 + lane) * 8;

  const _Float16* rowp[4];
  #pragma unroll
  for (int mi = 0; mi < 4; mi++)
    rowp[mi] = h5h + (size_t)(mblk * 64 + mi * 16 + l16) * 320;

  f4 acc[4][5];
  #pragma unroll
  for (int i = 0; i < 4; i++)
    #pragma unroll
    for (int j = 0; j < 5; j++) acc[i][j] = (f4){0.f, 0.f, 0.f, 0.f};

  h8 bb[4][5], vjC[4], vjN[4], hi8C[4], hi8N[4];

  #define LOADB7(DST, POS)                                                     \
    _Pragma("unroll")                                                          \
    for (int nt = 0; nt < 5; nt++)                                             \
      DST[nt] = *(const h8*)&wb[(size_t)(POS) * 10240 + nt * 512];

  // initial c-block state for pos0 (cum(c) = 16*c*(c+1))
  int c = 0, cend = 32;
  while (pos0 >= cend) { c++; cend = (c < 9) ? 16 * (c + 1) * (c + 2) : NPOS; }
  int cumc = 16 * c * (c + 1);
  #pragma unroll
  for (int mi = 0; mi < 4; mi++) {
    vjC[mi]  = *(const h8*)&rowp[mi][c * 32 + quad * 8];
    hi8C[mi] = *(const h8*)&rowp[mi][pos0 - cumc];
  }
  #pragma unroll
  for (int q = 0; q < 4; q++) { LOADB7(bb[q], pos0 + q); }

  for (int p = pos0; p < pos1; p += 8) {
    const int pn = p + 8;
    // prefetch next group's A-side state (consumed one group later)
    int cN = c, cendN = cend, cumcN = cumc;
    bool adv = false;
    if (pn < pos1) {
      while (pn >= cendN) {
        cN++; cendN = (cN < 9) ? 16 * (cN + 1) * (cN + 2) : NPOS; adv = true;
      }
      if (adv) cumcN = 16 * cN * (cN + 1);
      #pragma unroll
      for (int mi = 0; mi < 4; mi++)
        hi8N[mi] = *(const h8*)&rowp[mi][pn - cumcN];
      if (adv) {
        #pragma unroll
        for (int mi = 0; mi < 4; mi++)
          vjN[mi] = *(const h8*)&rowp[mi][cN * 32 + quad * 8];
      }
    }
    // 8 positions, 4-buffer rotation, B prefetch distance 4
    #pragma unroll
    for (int t = 0; t < 8; t++) {
      #pragma unroll
      for (int mi = 0; mi < 4; mi++) {
        _Float16 hsc = hi8C[mi][t];
        h8 hs = {hsc, hsc, hsc, hsc, hsc, hsc, hsc, hsc};
        h8 af = vjC[mi] * hs;
        #pragma unroll
        for (int nt = 0; nt < 5; nt++)
          acc[mi][nt] = __builtin_amdgcn_mfma_f32_16x16x32_f16(af, bb[t & 3][nt], acc[mi][nt], 0, 0, 0);
      }
      LOADB7(bb[t & 3], p + t + 4);
    }
    // rotate A-side state
    if (pn < pos1) {
      #pragma unroll
      for (int mi = 0; mi < 4; mi++) hi8C[mi] = hi8N[mi];
      if (adv) {
        #pragma unroll
        for (int mi = 0; mi < 4; mi++) vjC[mi] = vjN[mi];
        c = cN; cend = cendN; cumc = cumcN;
      }
    }
  }
  #undef LOADB7

  float* dst = part + (size_t)ks * (B_ * E_);
  #pragma unroll
  for (int mi = 0; mi < 4; mi++) {
    int b = mblk * 64 + mi * 16 + quad * 4;
    #pragma unroll
    for (int nt = 0; nt < 5; nt++) {
      int e = (gbase + nt) * 16 + l16;
      if (e < E_) {
        #pragma unroll
        for (int r = 0; r < 4; r++)
          dst[(size_t)(b + r) * E_ + e] = acc[mi][nt][r];
      }
    }
  }
}

extern "C" void kernel_launch(void* const* d_in, const int* in_sizes, int n_in,
                              void* d_out, int out_size, void* d_ws, size_t ws_size,
                              hipStream_t stream) {
  const float* x    = (const float*)d_in[0];
  const float* lemb = (const float*)d_in[1];
  const float* fc1w = (const float*)d_in[2];
  const float* fc1b = (const float*)d_in[3];
  const float* q1   = (const float*)d_in[4];
  const float* fc3w = (const float*)d_in[5];
  const float* fc3b = (const float*)d_in[6];
  const float* q2   = (const float*)d_in[7];
  const float* fc5w = (const float*)d_in[8];
  const float* fc6w = (const float*)d_in[10];
  const float* fc7w = (const float*)d_in[12];
  const float* fc8w = (const float*)d_in[14];
  const float* fc8b = (const float*)d_in[15];
  const float* v    = (const float*)d_in[16];
  float* out = (float*)d_out;
  (void)in_sizes; (void)n_in; (void)out_size; (void)ws_size;

  char* base = (char*)d_ws;
  size_t off = 0;
  auto alloc = [&](size_t nbytes) -> char* {
    char* p = base + off;
    off = (off + nbytes + 255) & ~(size_t)255;
    return p;
  };
  _Float16*  Wgf   = (_Float16*) alloc((size_t)(NPOS + 8) * 20 * 64 * 8 * 2);  // 35.9 MB (+prefetch slack)
  _Float16*  Wf5   = (_Float16*) alloc((size_t)19 * 19 * 512 * 2);
  _Float16*  Wf6   = (_Float16*) alloc((size_t)10 * 19 * 512 * 2);
  _Float16*  Wf8   = (_Float16*) alloc((size_t)19 * 19 * 512 * 2);
  _Float16*  WfL   = (_Float16*) alloc((size_t)10 * 63 * 512 * 2);
  _Float16*  hh    = (_Float16*) alloc((size_t)B_ * 608 * 2);
  _Float16*  h5h   = (_Float16*) alloc((size_t)B_ * 320 * 2);
  _Float16*  hcath = (_Float16*) alloc((size_t)B_ * 608 * 2);
  _Float16*  out8h = (_Float16*) alloc((size_t)B_ * 320 * 2);
  float*     pre   = (float*)    alloc((size_t)B_ * E_ * 4);   // shared h5pre/h6pre/h7pre
  float*     cpart = (float*)    alloc((size_t)RSBLK * E_ * 2 * 4);  // 1.23 MB
  float*     cstat = (float*)    alloc((size_t)E_ * 2 * 4);
  size_t part_bytes = (size_t)BKSPLIT * B_ * E_ * 4;           // 39.3 MB
  char* scratch = alloc(part_bytes);
  float* a     = (float*)scratch;                              // [R_][16] 6.55 MB (phase 1)
  float* sabs  = a + (size_t)R_ * 16;
  float* spart = sabs + R_;                                    // [2][S][4][2]
  float* part  = (float*)scratch;                              // reused after k_pool

  // fused prep: Wgf + all weight conversions (one dispatch)
  hipLaunchKernelGGL(k_prep, dim3(NPOS * 5 + 95 + 50 + 95 + 160), dim3(256), 0, stream,
                     fc7w, v, Wgf, fc5w, Wf5, fc6w, Wf6, fc8w, Wf8, lemb, WfL);
  // attention pools
  hipLaunchKernelGGL(k_attn2, dim3(R_ / 128), dim3(256), 0, stream, x, fc1w, fc1b, fc3w, fc3b, a, sabs);
  hipLaunchKernelGGL(k_attnstats, dim3(S_, 2, 4), dim3(256), 0, stream, a, spart);
  hipLaunchKernelGGL(k_pool, dim3(B_), dim3(256), 0, stream, x, a, sabs, spart, q1, q2, hh);
  // fc5 (f16 MFMA, ksplit 4) + BN -> h5h
  hipLaunchKernelGGL(k_gemmf, dim3(32, 2, 4), dim3(256), 0, stream, hh, 608, Wf5, 19, part, 300, 19, 5);
  hipLaunchKernelGGL(k_reduce_stat, dim3(RSBLK), dim3(256), 0, stream, part, pre, cpart, 4);
  hipLaunchKernelGGL(k_colstat_fin, dim3(E_), dim3(256), 0, stream, cpart, cstat, E_, RSBLK, B_);
  hipLaunchKernelGGL(k_norm_h5h, dim3((B_ * 320) / 256), dim3(256), 0, stream, pre, cstat, h5h);
  // fc6 + BN -> hcath[:, :300]
  hipLaunchKernelGGL(k_gemmf, dim3(32, 2, 4), dim3(256), 0, stream, h5h, 320, Wf6, 19, part, 300, 10, 3);
  hipLaunchKernelGGL(k_reduce_stat, dim3(RSBLK), dim3(256), 0, stream, part, pre, cpart, 4);
  hipLaunchKernelGGL(k_colstat_fin, dim3(E_), dim3(256), 0, stream, cpart, cstat, E_, RSBLK, B_);
  hipLaunchKernelGGL(k_norm_hcat, dim3((B_ * 300 + 255) / 256), dim3(256), 0, stream, pre, cstat, hcath, 0, 0);
  // cross-feature GEMM v7 + BN -> hcath[:, 300:] (+pad)
  hipLaunchKernelGGL(k_bigmm7, dim3(BKSPLIT * 32), dim3(256), 0, stream, Wgf, h5h, part);
  hipLaunchKernelGGL(k_reduce_stat, dim3(RSBLK), dim3(256), 0, stream, part, pre, cpart, BKSPLIT);
  hipLaunchKernelGGL(k_colstat_fin, dim3(E_), dim3(256), 0, stream, cpart, cstat, E_, RSBLK, B_);
  hipLaunchKernelGGL(k_norm_hcat, dim3((B_ * 308 + 255) / 256), dim3(256), 0, stream, pre, cstat, hcath, 300, 8);
  // fc8 (ksplit 4) + bias -> out8h f16
  hipLaunchKernelGGL(k_gemmf, dim3(32, 2, 4), dim3(256), 0, stream, hcath, 608, Wf8, 19, part, 300, 19, 5);
  hipLaunchKernelGGL(k_redbias_h, dim3((B_ * 320) / 256), dim3(256), 0, stream, part, fc8b, out8h, 4);
  // label projection (direct f32 out)
  hipLaunchKernelGGL(k_gemmf, dim3(32, 7, 1), dim3(256), 0, stream, out8h, 320, WfL, 63, out, 1000, 10, 10);
}